// Round 1
// baseline (16438.579 us; speedup 1.0000x reference)
//
#include <hip/hip_runtime.h>
#include <hip/hip_bf16.h>
#include <stdint.h>

// MLA forward, B=2 S=2048 DIM=2048 NH=16 HD=128 HDR=64 DCKV=512 DCQ=1536
// Round 1: correctness-first. bf16 MFMA GEMMs + VALU flash attention.
//
// NOTE the reference's reshape quirk: q = concat([uq(2048), rq(1024)]).reshape(...,16,192)
// -> head h owns FLAT dims [192h,192h+192) of the concat (same for k).

typedef __bf16 bf16x8 __attribute__((ext_vector_type(8)));
typedef float  f32x4  __attribute__((ext_vector_type(4)));

__device__ __forceinline__ uint16_t f2bf(float f) {
    uint32_t u = __builtin_bit_cast(uint32_t, f);
    u = (u + 0x7FFFu + ((u >> 16) & 1u)) >> 16;
    return (uint16_t)u;
}
__device__ __forceinline__ float bf2f(uint16_t h) {
    uint32_t u = ((uint32_t)h) << 16;
    return __builtin_bit_cast(float, u);
}

// ---------------------------------------------------------------------------
// GEMM: C(M,N) = A(M,K) @ W(N,K)^T + bias
// A: fp32 (A_F32) or bf16 bits. W, bias: fp32. K % 32 == 0, M % 128 == 0.
// MODE 0: bf16 row-major MxN
// MODE 1: qk-pack: flat n -> head n/192, d n%192; out[(b*16+h)*2048+s][192] bf16
// MODE 2: v-pack:  head n>>7, d n&127; stride 128 bf16
// MODE 3: fp32 row-major MxN (final output)
// ---------------------------------------------------------------------------
template<int MODE, bool A_F32>
__global__ __launch_bounds__(256)
void gemm_kernel(const void* __restrict__ Aptr, const float* __restrict__ W,
                 const float* __restrict__ bias, void* __restrict__ Out,
                 int M, int N, int K)
{
    __shared__ uint16_t Alds[128][40];
    __shared__ uint16_t Blds[128][40];

    const int tid  = threadIdx.x;
    const int lane = tid & 63;
    const int wave = tid >> 6;
    const int wm   = wave >> 1;
    const int wn   = wave & 1;
    const int m0   = blockIdx.y << 7;
    const int n0   = blockIdx.x << 7;

    f32x4 acc[4][4];
    #pragma unroll
    for (int i = 0; i < 4; ++i)
        #pragma unroll
        for (int j = 0; j < 4; ++j)
            acc[i][j] = (f32x4){0.f, 0.f, 0.f, 0.f};

    const int rsel = lane & 15;
    const int ksel = (lane >> 4) << 3;

    const int nK = K >> 5;
    for (int kt = 0; kt < nK; ++kt) {
        const int k0 = kt << 5;
        // stage A tile (128 x 32)
        #pragma unroll
        for (int j = 0; j < 4; ++j) {
            int c   = tid + j * 256;     // 0..1023
            int row = c >> 3;
            int col = (c & 7) << 2;
            if (A_F32) {
                const float* Af = (const float*)Aptr;
                const float4 v = *(const float4*)(Af + (size_t)(m0 + row) * K + k0 + col);
                ushort4 o;
                o.x = f2bf(v.x); o.y = f2bf(v.y); o.z = f2bf(v.z); o.w = f2bf(v.w);
                *(ushort4*)&Alds[row][col] = o;
            } else {
                const uint16_t* Ah = (const uint16_t*)Aptr;
                *(ushort4*)&Alds[row][col] = *(const ushort4*)(Ah + (size_t)(m0 + row) * K + k0 + col);
            }
        }
        // stage B tile (128 x 32) from W (N,K), zero-fill rows >= N
        #pragma unroll
        for (int j = 0; j < 4; ++j) {
            int c   = tid + j * 256;
            int row = c >> 3;
            int col = (c & 7) << 2;
            int n   = n0 + row;
            ushort4 o;
            if (n < N) {
                const float4 v = *(const float4*)(W + (size_t)n * K + k0 + col);
                o.x = f2bf(v.x); o.y = f2bf(v.y); o.z = f2bf(v.z); o.w = f2bf(v.w);
            } else {
                o.x = 0; o.y = 0; o.z = 0; o.w = 0;
            }
            *(ushort4*)&Blds[row][col] = o;
        }
        __syncthreads();

        bf16x8 af[4], bfr[4];
        #pragma unroll
        for (int i = 0; i < 4; ++i)
            af[i] = *(const bf16x8*)&Alds[(wm << 6) + (i << 4) + rsel][ksel];
        #pragma unroll
        for (int j = 0; j < 4; ++j)
            bfr[j] = *(const bf16x8*)&Blds[(wn << 6) + (j << 4) + rsel][ksel];

        #pragma unroll
        for (int i = 0; i < 4; ++i)
            #pragma unroll
            for (int j = 0; j < 4; ++j)
                acc[i][j] = __builtin_amdgcn_mfma_f32_16x16x32_bf16(af[i], bfr[j], acc[i][j], 0, 0, 0);
        __syncthreads();
    }

    // epilogue: D lane map: col = lane&15, row = 4*(lane>>4)+r
    const int col = lane & 15;
    const int rg  = lane >> 4;
    #pragma unroll
    for (int i = 0; i < 4; ++i) {
        #pragma unroll
        for (int j = 0; j < 4; ++j) {
            int n = n0 + (wn << 6) + (j << 4) + col;
            if (n >= N) continue;
            float bv = bias[n];
            #pragma unroll
            for (int r = 0; r < 4; ++r) {
                int m = m0 + (wm << 6) + (i << 4) + (rg << 2) + r;
                float v = acc[i][j][r] + bv;
                if (MODE == 0) {
                    ((uint16_t*)Out)[(size_t)m * N + n] = f2bf(v);
                } else if (MODE == 1) {
                    int h = n / 192, d = n - h * 192;
                    int b = m >> 11, s = m & 2047;
                    ((uint16_t*)Out)[(((size_t)(b * 16 + h) * 2048 + s) * 192) + d] = f2bf(v);
                } else if (MODE == 2) {
                    int h = n >> 7, d = n & 127;
                    int b = m >> 11, s = m & 2047;
                    ((uint16_t*)Out)[(((size_t)(b * 16 + h) * 2048 + s) * 128) + d] = f2bf(v);
                } else {
                    ((float*)Out)[(size_t)m * N + n] = v;
                }
            }
        }
    }
}

// ---------------------------------------------------------------------------
// RoPE for q rope-part: raw (4096,1024) bf16, flat concat offset = 2048 + h*64 + d
// ---------------------------------------------------------------------------
__global__ __launch_bounds__(256)
void rope_q_kernel(const uint16_t* __restrict__ raw, const float* __restrict__ fc,
                   const float* __restrict__ fs, uint16_t* __restrict__ qp)
{
    int gid = blockIdx.x * 256 + threadIdx.x;      // over 4096*1024
    int m = gid >> 10, n = gid & 1023;
    int hh = n >> 6, d = n & 63;
    int b = m >> 11, s = m & 2047;
    float x  = bf2f(raw[(size_t)m * 1024 + n]);
    float xo = bf2f(raw[(size_t)m * 1024 + hh * 64 + ((d < 32) ? d + 32 : d - 32)]);
    float rot = (d < 32) ? -xo : xo;
    float v = x * fc[s * 64 + d] + rot * fs[s * 64 + d];
    int f = 2048 + n;                              // flat concat index
    int head = f / 192, dq = f - head * 192;
    qp[(((size_t)(b * 16 + head) * 2048 + s) * 192) + dq] = f2bf(v);
}

// RoPE for k rope-part: raw (4096,64) bf16, broadcast to flat 2048 + h*64 + d, all h
__global__ __launch_bounds__(256)
void rope_k_kernel(const uint16_t* __restrict__ raw, const float* __restrict__ fc,
                   const float* __restrict__ fs, uint16_t* __restrict__ kp)
{
    int gid = blockIdx.x * 256 + threadIdx.x;      // over 4096*64
    int m = gid >> 6, d = gid & 63;
    int b = m >> 11, s = m & 2047;
    float x  = bf2f(raw[(size_t)m * 64 + d]);
    float xo = bf2f(raw[(size_t)m * 64 + ((d < 32) ? d + 32 : d - 32)]);
    float rot = (d < 32) ? -xo : xo;
    uint16_t bv = f2bf(x * fc[s * 64 + d] + rot * fs[s * 64 + d]);
    #pragma unroll
    for (int hh = 0; hh < 16; ++hh) {
        int f = 2048 + hh * 64 + d;
        int head = f / 192, dk = f - head * 192;
        kp[(((size_t)(b * 16 + head) * 2048 + s) * 192) + dk] = bv;
    }
}

// ---------------------------------------------------------------------------
// Flash attention (causal), VALU version. Block = 4 waves; wave owns 4 q rows.
// q/k per-head dim 192, v dim 128. Online softmax base-2.
// ---------------------------------------------------------------------------
__global__ __launch_bounds__(256)
void attn_kernel(const uint16_t* __restrict__ qp, const uint16_t* __restrict__ kp,
                 const uint16_t* __restrict__ vp, uint16_t* __restrict__ yf)
{
    __shared__ float    qs[16][192];
    __shared__ uint16_t Ks[64][196];   // pad 196: 2-way (free) on u32 reads
    __shared__ uint16_t Vs[64][132];   // pad 132: conflict-free on u32 reads
    __shared__ float    ps[4][4][64];

    const int tid  = threadIdx.x;
    const int lane = tid & 63;
    const int w    = tid >> 6;
    const int bh   = blockIdx.y;
    const int b    = bh >> 4;
    const int h    = bh & 15;
    const int q0   = blockIdx.x << 4;

    const size_t qkbase = (size_t)bh * 2048 * 192;
    const size_t vbase  = (size_t)bh * 2048 * 128;

    for (int idx = tid; idx < 16 * 192; idx += 256) {
        int r = idx / 192, d = idx - r * 192;
        qs[r][d] = bf2f(qp[qkbase + (size_t)(q0 + r) * 192 + d]);
    }

    const int rowbase = q0 + (w << 2);
    float mstate[4], lstate[4], o0[4], o1[4];
    #pragma unroll
    for (int i = 0; i < 4; ++i) { mstate[i] = -__builtin_inff(); lstate[i] = 0.f; o0[i] = 0.f; o1[i] = 0.f; }
    const float scl = 0.07216878364870323f * 1.4426950408889634f;  // 1/sqrt(192) * log2(e)

    const int ntiles = (q0 + 16 + 63) >> 6;
    for (int t = 0; t < ntiles; ++t) {
        const int j0 = t << 6;
        __syncthreads();
        for (int idx = tid; idx < 64 * 48; idx += 256) {
            int r = idx / 48, c4 = (idx - r * 48) << 2;
            *(ushort4*)&Ks[r][c4] = *(const ushort4*)&kp[qkbase + (size_t)(j0 + r) * 192 + c4];
        }
        for (int idx = tid; idx < 64 * 32; idx += 256) {
            int r = idx >> 5, c4 = (idx & 31) << 2;
            *(ushort4*)&Vs[r][c4] = *(const ushort4*)&vp[vbase + (size_t)(j0 + r) * 128 + c4];
        }
        __syncthreads();

        // scores: lane's kv row = j0 + lane
        float sc[4] = {0.f, 0.f, 0.f, 0.f};
        const uint32_t* krow = (const uint32_t*)&Ks[lane][0];
        #pragma unroll
        for (int cc = 0; cc < 12; ++cc) {
            float kf[16];
            #pragma unroll
            for (int u = 0; u < 8; ++u) {
                uint32_t kk = krow[cc * 8 + u];
                kf[2 * u]     = __builtin_bit_cast(float, kk << 16);
                kf[2 * u + 1] = __builtin_bit_cast(float, kk & 0xffff0000u);
            }
            #pragma unroll
            for (int i = 0; i < 4; ++i) {
                const float* qr = &qs[(w << 2) + i][cc * 16];
                #pragma unroll
                for (int u = 0; u < 16; ++u) sc[i] += qr[u] * kf[u];
            }
        }

        float corr[4];
        #pragma unroll
        for (int i = 0; i < 4; ++i) {
            const int qrow = rowbase + i;
            float s = (j0 + lane <= qrow) ? sc[i] * scl : -__builtin_inff();
            float tm = s;
            #pragma unroll
            for (int off = 32; off > 0; off >>= 1) tm = fmaxf(tm, __shfl_xor(tm, off, 64));
            float p, c;
            if (tm == -__builtin_inff()) {
                p = 0.f; c = 1.f;                          // wave-uniform: tile fully masked for this row
            } else {
                float mnew = fmaxf(mstate[i], tm);
                c = exp2f(mstate[i] - mnew);
                p = exp2f(s - mnew);
                mstate[i] = mnew;
            }
            float psum = p;
            #pragma unroll
            for (int off = 32; off > 0; off >>= 1) psum += __shfl_xor(psum, off, 64);
            lstate[i] = lstate[i] * c + psum;
            corr[i] = c;
            ps[w][i][lane] = p;
        }

        // PV: lane owns output dims {2*lane, 2*lane+1}
        float a0[4] = {0.f, 0.f, 0.f, 0.f}, a1[4] = {0.f, 0.f, 0.f, 0.f};
        #pragma unroll
        for (int kc = 0; kc < 8; ++kc) {
            float vf0[8], vf1[8];
            #pragma unroll
            for (int u = 0; u < 8; ++u) {
                uint32_t vv = *(const uint32_t*)&Vs[kc * 8 + u][lane << 1];
                vf0[u] = __builtin_bit_cast(float, vv << 16);
                vf1[u] = __builtin_bit_cast(float, vv & 0xffff0000u);
            }
            #pragma unroll
            for (int i = 0; i < 4; ++i) {
                float pk[8];
                #pragma unroll
                for (int u = 0; u < 8; ++u) pk[u] = ps[w][i][kc * 8 + u];
                #pragma unroll
                for (int u = 0; u < 8; ++u) { a0[i] += pk[u] * vf0[u]; a1[i] += pk[u] * vf1[u]; }
            }
        }
        #pragma unroll
        for (int i = 0; i < 4; ++i) {
            o0[i] = o0[i] * corr[i] + a0[i];
            o1[i] = o1[i] * corr[i] + a1[i];
        }
    }

    #pragma unroll
    for (int i = 0; i < 4; ++i) {
        float inv = 1.f / lstate[i];
        int srow = rowbase + i;
        uint32_t outw = (uint32_t)f2bf(o0[i] * inv) | ((uint32_t)f2bf(o1[i] * inv) << 16);
        *(uint32_t*)&yf[((size_t)(b * 2048 + srow) * 2048) + h * 128 + (lane << 1)] = outw;
    }
}

// ---------------------------------------------------------------------------
extern "C" void kernel_launch(void* const* d_in, const int* in_sizes, int n_in,
                              void* d_out, int out_size, void* d_ws, size_t ws_size,
                              hipStream_t stream)
{
    const float* x     = (const float*)d_in[0];
    const float* fcos  = (const float*)d_in[1];
    const float* fsin  = (const float*)d_in[2];
    const float* W_dq  = (const float*)d_in[3];
    const float* b_dq  = (const float*)d_in[4];
    const float* W_uq  = (const float*)d_in[5];
    const float* b_uq  = (const float*)d_in[6];
    const float* W_qr  = (const float*)d_in[7];
    const float* b_qr  = (const float*)d_in[8];
    const float* W_dkv = (const float*)d_in[9];
    const float* b_dkv = (const float*)d_in[10];
    const float* W_uk  = (const float*)d_in[11];
    const float* b_uk  = (const float*)d_in[12];
    const float* W_uv  = (const float*)d_in[13];
    const float* b_uv  = (const float*)d_in[14];
    const float* W_kr  = (const float*)d_in[15];
    const float* b_kr  = (const float*)d_in[16];
    const float* W_out = (const float*)d_in[17];
    const float* b_out = (const float*)d_in[18];

    char* ws = (char*)d_ws;
    uint16_t* c_q    = (uint16_t*)(ws + 0);            // 4096x1536 bf16
    uint16_t* c_kv   = (uint16_t*)(ws + 12582912);     // 4096x512
    uint16_t* qr_raw = (uint16_t*)(ws + 16777216);     // 4096x1024
    uint16_t* kr_raw = (uint16_t*)(ws + 25165824);     // 4096x64
    uint16_t* qp     = (uint16_t*)(ws + 25690112);     // (2,16,2048,192)
    uint16_t* kp     = (uint16_t*)(ws + 50855936);     // (2,16,2048,192)
    uint16_t* vp     = (uint16_t*)(ws + 76021760);     // (2,16,2048,128)
    uint16_t* yf     = (uint16_t*)(ws + 92798976);     // 4096x2048

    dim3 blk(256);
    gemm_kernel<0, true ><<<dim3(12, 32), blk, 0, stream>>>(x,    W_dq,  b_dq,  c_q,    4096, 1536, 2048);
    gemm_kernel<0, true ><<<dim3( 4, 32), blk, 0, stream>>>(x,    W_dkv, b_dkv, c_kv,   4096,  512, 2048);
    gemm_kernel<0, true ><<<dim3( 1, 32), blk, 0, stream>>>(x,    W_kr,  b_kr,  kr_raw, 4096,   64, 2048);
    gemm_kernel<1, false><<<dim3(16, 32), blk, 0, stream>>>(c_q,  W_uq,  b_uq,  qp,     4096, 2048, 1536);
    gemm_kernel<0, false><<<dim3( 8, 32), blk, 0, stream>>>(c_q,  W_qr,  b_qr,  qr_raw, 4096, 1024, 1536);
    gemm_kernel<1, false><<<dim3(16, 32), blk, 0, stream>>>(c_kv, W_uk,  b_uk,  kp,     4096, 2048,  512);
    gemm_kernel<2, false><<<dim3(16, 32), blk, 0, stream>>>(c_kv, W_uv,  b_uv,  vp,     4096, 2048,  512);
    rope_q_kernel<<<dim3(16384), blk, 0, stream>>>(qr_raw, fcos, fsin, qp);
    rope_k_kernel<<<dim3(1024),  blk, 0, stream>>>(kr_raw, fcos, fsin, kp);
    attn_kernel<<<dim3(128, 32), blk, 0, stream>>>(qp, kp, vp, yf);
    gemm_kernel<3, false><<<dim3(16, 32), blk, 0, stream>>>(yf, W_out, b_out, d_out, 4096, 2048, 2048);
}

// Round 2
// 1325.849 us; speedup vs baseline: 12.3985x; 12.3985x over previous
//
#include <hip/hip_runtime.h>
#include <hip/hip_bf16.h>
#include <stdint.h>

// MLA forward, B=2 S=2048 DIM=2048 NH=16 HD=128 HDR=64 DCKV=512 DCQ=1536
// Round 2: MFMA flash attention (the 15.4ms VALU attn was 94% of runtime,
// scratch-spilling 30GB). GEMMs unchanged from R1 (passed).
//
// NOTE the reference's reshape quirk: q = concat([uq(2048), rq(1024)]).reshape(...,16,192)
// -> head h owns FLAT dims [192h,192h+192) of the concat (same for k).

typedef __bf16 bf16x8 __attribute__((ext_vector_type(8)));
typedef float  f32x4  __attribute__((ext_vector_type(4)));

__device__ __forceinline__ uint16_t f2bf(float f) {
    uint32_t u = __builtin_bit_cast(uint32_t, f);
    u = (u + 0x7FFFu + ((u >> 16) & 1u)) >> 16;
    return (uint16_t)u;
}
__device__ __forceinline__ float bf2f(uint16_t h) {
    uint32_t u = ((uint32_t)h) << 16;
    return __builtin_bit_cast(float, u);
}

// ---------------------------------------------------------------------------
// GEMM: C(M,N) = A(M,K) @ W(N,K)^T + bias   (unchanged from R1)
// ---------------------------------------------------------------------------
template<int MODE, bool A_F32>
__global__ __launch_bounds__(256)
void gemm_kernel(const void* __restrict__ Aptr, const float* __restrict__ W,
                 const float* __restrict__ bias, void* __restrict__ Out,
                 int M, int N, int K)
{
    __shared__ uint16_t Alds[128][40];
    __shared__ uint16_t Blds[128][40];

    const int tid  = threadIdx.x;
    const int lane = tid & 63;
    const int wave = tid >> 6;
    const int wm   = wave >> 1;
    const int wn   = wave & 1;
    const int m0   = blockIdx.y << 7;
    const int n0   = blockIdx.x << 7;

    f32x4 acc[4][4];
    #pragma unroll
    for (int i = 0; i < 4; ++i)
        #pragma unroll
        for (int j = 0; j < 4; ++j)
            acc[i][j] = (f32x4){0.f, 0.f, 0.f, 0.f};

    const int rsel = lane & 15;
    const int ksel = (lane >> 4) << 3;

    const int nK = K >> 5;
    for (int kt = 0; kt < nK; ++kt) {
        const int k0 = kt << 5;
        #pragma unroll
        for (int j = 0; j < 4; ++j) {
            int c   = tid + j * 256;
            int row = c >> 3;
            int col = (c & 7) << 2;
            if (A_F32) {
                const float* Af = (const float*)Aptr;
                const float4 v = *(const float4*)(Af + (size_t)(m0 + row) * K + k0 + col);
                ushort4 o;
                o.x = f2bf(v.x); o.y = f2bf(v.y); o.z = f2bf(v.z); o.w = f2bf(v.w);
                *(ushort4*)&Alds[row][col] = o;
            } else {
                const uint16_t* Ah = (const uint16_t*)Aptr;
                *(ushort4*)&Alds[row][col] = *(const ushort4*)(Ah + (size_t)(m0 + row) * K + k0 + col);
            }
        }
        #pragma unroll
        for (int j = 0; j < 4; ++j) {
            int c   = tid + j * 256;
            int row = c >> 3;
            int col = (c & 7) << 2;
            int n   = n0 + row;
            ushort4 o;
            if (n < N) {
                const float4 v = *(const float4*)(W + (size_t)n * K + k0 + col);
                o.x = f2bf(v.x); o.y = f2bf(v.y); o.z = f2bf(v.z); o.w = f2bf(v.w);
            } else {
                o.x = 0; o.y = 0; o.z = 0; o.w = 0;
            }
            *(ushort4*)&Blds[row][col] = o;
        }
        __syncthreads();

        bf16x8 af[4], bfr[4];
        #pragma unroll
        for (int i = 0; i < 4; ++i)
            af[i] = *(const bf16x8*)&Alds[(wm << 6) + (i << 4) + rsel][ksel];
        #pragma unroll
        for (int j = 0; j < 4; ++j)
            bfr[j] = *(const bf16x8*)&Blds[(wn << 6) + (j << 4) + rsel][ksel];

        #pragma unroll
        for (int i = 0; i < 4; ++i)
            #pragma unroll
            for (int j = 0; j < 4; ++j)
                acc[i][j] = __builtin_amdgcn_mfma_f32_16x16x32_bf16(af[i], bfr[j], acc[i][j], 0, 0, 0);
        __syncthreads();
    }

    const int col = lane & 15;
    const int rg  = lane >> 4;
    #pragma unroll
    for (int i = 0; i < 4; ++i) {
        #pragma unroll
        for (int j = 0; j < 4; ++j) {
            int n = n0 + (wn << 6) + (j << 4) + col;
            if (n >= N) continue;
            float bv = bias[n];
            #pragma unroll
            for (int r = 0; r < 4; ++r) {
                int m = m0 + (wm << 6) + (i << 4) + (rg << 2) + r;
                float v = acc[i][j][r] + bv;
                if (MODE == 0) {
                    ((uint16_t*)Out)[(size_t)m * N + n] = f2bf(v);
                } else if (MODE == 1) {
                    int h = n / 192, d = n - h * 192;
                    int b = m >> 11, s = m & 2047;
                    ((uint16_t*)Out)[(((size_t)(b * 16 + h) * 2048 + s) * 192) + d] = f2bf(v);
                } else if (MODE == 2) {
                    int h = n >> 7, d = n & 127;
                    int b = m >> 11, s = m & 2047;
                    ((uint16_t*)Out)[(((size_t)(b * 16 + h) * 2048 + s) * 128) + d] = f2bf(v);
                } else {
                    ((float*)Out)[(size_t)m * N + n] = v;
                }
            }
        }
    }
}

// ---------------------------------------------------------------------------
// RoPE kernels (unchanged from R1)
// ---------------------------------------------------------------------------
__global__ __launch_bounds__(256)
void rope_q_kernel(const uint16_t* __restrict__ raw, const float* __restrict__ fc,
                   const float* __restrict__ fs, uint16_t* __restrict__ qp)
{
    int gid = blockIdx.x * 256 + threadIdx.x;
    int m = gid >> 10, n = gid & 1023;
    int hh = n >> 6, d = n & 63;
    int b = m >> 11, s = m & 2047;
    float x  = bf2f(raw[(size_t)m * 1024 + n]);
    float xo = bf2f(raw[(size_t)m * 1024 + hh * 64 + ((d < 32) ? d + 32 : d - 32)]);
    float rot = (d < 32) ? -xo : xo;
    float v = x * fc[s * 64 + d] + rot * fs[s * 64 + d];
    int f = 2048 + n;
    int head = f / 192, dq = f - head * 192;
    qp[(((size_t)(b * 16 + head) * 2048 + s) * 192) + dq] = f2bf(v);
}

__global__ __launch_bounds__(256)
void rope_k_kernel(const uint16_t* __restrict__ raw, const float* __restrict__ fc,
                   const float* __restrict__ fs, uint16_t* __restrict__ kp)
{
    int gid = blockIdx.x * 256 + threadIdx.x;
    int m = gid >> 6, d = gid & 63;
    int b = m >> 11, s = m & 2047;
    float x  = bf2f(raw[(size_t)m * 64 + d]);
    float xo = bf2f(raw[(size_t)m * 64 + ((d < 32) ? d + 32 : d - 32)]);
    float rot = (d < 32) ? -xo : xo;
    uint16_t bv = f2bf(x * fc[s * 64 + d] + rot * fs[s * 64 + d]);
    #pragma unroll
    for (int hh = 0; hh < 16; ++hh) {
        int f = 2048 + hh * 64 + d;
        int head = f / 192, dk = f - head * 192;
        kp[(((size_t)(b * 16 + head) * 2048 + s) * 192) + dk] = bv;
    }
}

// ---------------------------------------------------------------------------
// MFMA flash attention (causal). 4 waves; Q-tile 64 rows (16/wave); KV-tile 64.
// qk head dim 192, v dim 128. Online softmax base-2 in MFMA D-layout.
// Fragment maps (verified via gemm above): A: row=lane&15,k=8*(lane>>4)+j;
// B: col=lane&15,k=8*(lane>>4)+j; D: col=lane&15,row=4*(lane>>4)+r.
// ---------------------------------------------------------------------------
__global__ __launch_bounds__(256)
void attn_mfma_kernel(const uint16_t* __restrict__ qp, const uint16_t* __restrict__ kp,
                      const uint16_t* __restrict__ vp, uint16_t* __restrict__ yf)
{
    __shared__ uint16_t Ks[64][200];   // row stride 400B: 16B-aligned; bank stride 4 (<=2-way on frag reads)
    __shared__ uint16_t Vt[128][72];   // V transposed: Vt[d][kv]; stride 144B, 16B-aligned
    __shared__ uint16_t Ps[4][16][72]; // per-wave P buffer: D-layout -> A-frag layout bridge

    const int tid  = threadIdx.x;
    const int lane = tid & 63;
    const int w    = tid >> 6;
    const int g    = lane >> 4;        // 0..3
    const int li   = lane & 15;
    const int bh   = blockIdx.y;
    const int b    = bh >> 4;
    const int h    = bh & 15;
    const int qt   = gridDim.x - 1 - blockIdx.x;   // heavy tiles dispatch first
    const int q0   = qt << 6;

    const size_t qkbase = (size_t)bh * 2048 * 192;
    const size_t vbase  = (size_t)bh * 2048 * 128;

    // Q fragments for this wave's 16 rows, held in registers for the whole pass
    const int qfrow = q0 + (w << 4) + li;
    bf16x8 qf[6];
    #pragma unroll
    for (int kk = 0; kk < 6; ++kk)
        qf[kk] = *(const bf16x8*)(qp + qkbase + (size_t)qfrow * 192 + kk * 32 + g * 8);

    float mstate[4], lstate[4];
    f32x4 oacc[8];
    #pragma unroll
    for (int r = 0; r < 4; ++r) { mstate[r] = -__builtin_inff(); lstate[r] = 0.f; }
    #pragma unroll
    for (int ct = 0; ct < 8; ++ct) oacc[ct] = (f32x4){0.f, 0.f, 0.f, 0.f};

    const float scl = 0.07216878364870323f * 1.4426950408889634f;  // 1/sqrt(192) * log2(e)

    const int ntiles = qt + 1;
    for (int t = 0; t < ntiles; ++t) {
        const int j0 = t << 6;

        // stage K tile 64x192 (coalesced 16B chunks)
        #pragma unroll
        for (int p = 0; p < 6; ++p) {
            int idx = tid + p * 256;           // 0..1535 over 64 rows x 24 chunks
            int r = idx / 24, c8 = (idx - r * 24) << 3;
            *(bf16x8*)&Ks[r][c8] = *(const bf16x8*)(kp + qkbase + (size_t)(j0 + r) * 192 + c8);
        }
        // stage V transposed: Vt[d][kv]
        #pragma unroll
        for (int p = 0; p < 8; ++p) {
            int idx = tid + p * 256;           // 0..2047 over 64 rows x 32 chunks
            int r = idx >> 5, c4 = (idx & 31) << 2;
            ushort4 v = *(const ushort4*)(vp + vbase + (size_t)(j0 + r) * 128 + c4);
            Vt[c4 + 0][r] = v.x; Vt[c4 + 1][r] = v.y;
            Vt[c4 + 2][r] = v.z; Vt[c4 + 3][r] = v.w;
        }
        __syncthreads();

        // S = Q K^T : 4 col-tiles x 6 k-frags
        f32x4 sacc[4];
        #pragma unroll
        for (int c = 0; c < 4; ++c) sacc[c] = (f32x4){0.f, 0.f, 0.f, 0.f};
        #pragma unroll
        for (int c = 0; c < 4; ++c) {
            #pragma unroll
            for (int kk = 0; kk < 6; ++kk) {
                bf16x8 kf = *(const bf16x8*)&Ks[(c << 4) + li][kk * 32 + (g << 3)];
                sacc[c] = __builtin_amdgcn_mfma_f32_16x16x32_bf16(qf[kk], kf, sacc[c], 0, 0, 0);
            }
        }

        // online softmax (rows live in 16-lane groups; all 64 lanes active)
        float corr[4];
        #pragma unroll
        for (int r = 0; r < 4; ++r) {
            const int rq = q0 + (w << 4) + (g << 2) + r;
            float s[4];
            float mx = -__builtin_inff();
            #pragma unroll
            for (int c = 0; c < 4; ++c) {
                int colk = j0 + (c << 4) + li;
                s[c] = (colk <= rq) ? sacc[c][r] * scl : -__builtin_inff();
                mx = fmaxf(mx, s[c]);
            }
            #pragma unroll
            for (int off = 8; off >= 1; off >>= 1) mx = fmaxf(mx, __shfl_xor(mx, off, 64));
            float mnew = fmaxf(mstate[r], mx);
            corr[r] = exp2f(mstate[r] - mnew);
            mstate[r] = mnew;
            float psum = 0.f;
            #pragma unroll
            for (int c = 0; c < 4; ++c) {
                float p = exp2f(s[c] - mnew);
                psum += p;
                Ps[w][(g << 2) + r][(c << 4) + li] = f2bf(p);
            }
            #pragma unroll
            for (int off = 8; off >= 1; off >>= 1) psum += __shfl_xor(psum, off, 64);
            lstate[r] = lstate[r] * corr[r] + psum;
        }

        // O = O*corr + P V : 8 d-tiles x 2 k-frags
        #pragma unroll
        for (int ct = 0; ct < 8; ++ct) {
            #pragma unroll
            for (int r = 0; r < 4; ++r) oacc[ct][r] *= corr[r];
        }
        bf16x8 pf0 = *(const bf16x8*)&Ps[w][li][(g << 3)];
        bf16x8 pf1 = *(const bf16x8*)&Ps[w][li][32 + (g << 3)];
        #pragma unroll
        for (int ct = 0; ct < 8; ++ct) {
            bf16x8 vf0 = *(const bf16x8*)&Vt[(ct << 4) + li][(g << 3)];
            bf16x8 vf1 = *(const bf16x8*)&Vt[(ct << 4) + li][32 + (g << 3)];
            oacc[ct] = __builtin_amdgcn_mfma_f32_16x16x32_bf16(pf0, vf0, oacc[ct], 0, 0, 0);
            oacc[ct] = __builtin_amdgcn_mfma_f32_16x16x32_bf16(pf1, vf1, oacc[ct], 0, 0, 0);
        }
        __syncthreads();
    }

    #pragma unroll
    for (int r = 0; r < 4; ++r) {
        float inv = 1.f / lstate[r];
        int rq = q0 + (w << 4) + (g << 2) + r;
        size_t obase = ((size_t)(b * 2048 + rq) * 2048) + h * 128;
        #pragma unroll
        for (int ct = 0; ct < 8; ++ct)
            yf[obase + (ct << 4) + li] = f2bf(oacc[ct][r] * inv);
    }
}

// ---------------------------------------------------------------------------
extern "C" void kernel_launch(void* const* d_in, const int* in_sizes, int n_in,
                              void* d_out, int out_size, void* d_ws, size_t ws_size,
                              hipStream_t stream)
{
    const float* x     = (const float*)d_in[0];
    const float* fcos  = (const float*)d_in[1];
    const float* fsin  = (const float*)d_in[2];
    const float* W_dq  = (const float*)d_in[3];
    const float* b_dq  = (const float*)d_in[4];
    const float* W_uq  = (const float*)d_in[5];
    const float* b_uq  = (const float*)d_in[6];
    const float* W_qr  = (const float*)d_in[7];
    const float* b_qr  = (const float*)d_in[8];
    const float* W_dkv = (const float*)d_in[9];
    const float* b_dkv = (const float*)d_in[10];
    const float* W_uk  = (const float*)d_in[11];
    const float* b_uk  = (const float*)d_in[12];
    const float* W_uv  = (const float*)d_in[13];
    const float* b_uv  = (const float*)d_in[14];
    const float* W_kr  = (const float*)d_in[15];
    const float* b_kr  = (const float*)d_in[16];
    const float* W_out = (const float*)d_in[17];
    const float* b_out = (const float*)d_in[18];

    char* ws = (char*)d_ws;
    uint16_t* c_q    = (uint16_t*)(ws + 0);            // 4096x1536 bf16
    uint16_t* c_kv   = (uint16_t*)(ws + 12582912);     // 4096x512
    uint16_t* qr_raw = (uint16_t*)(ws + 16777216);     // 4096x1024
    uint16_t* kr_raw = (uint16_t*)(ws + 25165824);     // 4096x64
    uint16_t* qp     = (uint16_t*)(ws + 25690112);     // (2,16,2048,192)
    uint16_t* kp     = (uint16_t*)(ws + 50855936);     // (2,16,2048,192)
    uint16_t* vp     = (uint16_t*)(ws + 76021760);     // (2,16,2048,128)
    uint16_t* yf     = (uint16_t*)(ws + 92798976);     // 4096x2048

    dim3 blk(256);
    gemm_kernel<0, true ><<<dim3(12, 32), blk, 0, stream>>>(x,    W_dq,  b_dq,  c_q,    4096, 1536, 2048);
    gemm_kernel<0, true ><<<dim3( 4, 32), blk, 0, stream>>>(x,    W_dkv, b_dkv, c_kv,   4096,  512, 2048);
    gemm_kernel<0, true ><<<dim3( 1, 32), blk, 0, stream>>>(x,    W_kr,  b_kr,  kr_raw, 4096,   64, 2048);
    gemm_kernel<1, false><<<dim3(16, 32), blk, 0, stream>>>(c_q,  W_uq,  b_uq,  qp,     4096, 2048, 1536);
    gemm_kernel<0, false><<<dim3( 8, 32), blk, 0, stream>>>(c_q,  W_qr,  b_qr,  qr_raw, 4096, 1024, 1536);
    gemm_kernel<1, false><<<dim3(16, 32), blk, 0, stream>>>(c_kv, W_uk,  b_uk,  kp,     4096, 2048,  512);
    gemm_kernel<2, false><<<dim3(16, 32), blk, 0, stream>>>(c_kv, W_uv,  b_uv,  vp,     4096, 2048,  512);
    rope_q_kernel<<<dim3(16384), blk, 0, stream>>>(qr_raw, fcos, fsin, qp);
    rope_k_kernel<<<dim3(1024),  blk, 0, stream>>>(kr_raw, fcos, fsin, kp);
    attn_mfma_kernel<<<dim3(32, 32), blk, 0, stream>>>(qp, kp, vp, yf);
    gemm_kernel<3, false><<<dim3(16, 32), blk, 0, stream>>>(yf, W_out, b_out, d_out, 4096, 2048, 2048);
}

// Round 6
// 679.071 us; speedup vs baseline: 24.2074x; 1.9524x over previous
//
#include <hip/hip_runtime.h>
#include <hip/hip_bf16.h>
#include <stdint.h>

// MLA forward, B=2 S=2048 DIM=2048 NH=16 HD=128 HDR=64 DCKV=512 DCQ=1536
// Round 6: R3-R5's identical failure root-caused: conv_kernel for W_uk/W_uv
// passed 524288 instead of 1048576 elements (2048x512) -> heads 8-15 of
// k_base/v read 0xAA-poison weights. Two-line fix on the R5 source.
//
// Reference reshape quirk: q = concat([uq(2048), rq(1024)]).reshape(...,16,192)
// -> head h owns FLAT dims [192h,192h+192) of the concat (same for k).

typedef __bf16 bf16x8 __attribute__((ext_vector_type(8)));
typedef float  f32x4  __attribute__((ext_vector_type(4)));

__device__ __forceinline__ uint16_t f2bf(float f) {
    uint32_t u = __builtin_bit_cast(uint32_t, f);
    u = (u + 0x7FFFu + ((u >> 16) & 1u)) >> 16;
    return (uint16_t)u;
}
__device__ __forceinline__ float bf2f(uint16_t h) {
    uint32_t u = ((uint32_t)h) << 16;
    return __builtin_bit_cast(float, u);
}

// ---------------------------------------------------------------------------
// fp32 -> bf16 conversion (zero-fills dst beyond n_src, for padded W_kr)
// ---------------------------------------------------------------------------
__global__ __launch_bounds__(256)
void conv_kernel(const float* __restrict__ src, uint16_t* __restrict__ dst,
                 int n_src, int n_dst)
{
    int i = (blockIdx.x * 256 + threadIdx.x) << 2;
    if (i >= n_dst) return;
    ushort4 o;
    if (i < n_src) {
        float4 v = *(const float4*)(src + i);
        o.x = f2bf(v.x); o.y = f2bf(v.y); o.z = f2bf(v.z); o.w = f2bf(v.w);
    } else {
        o.x = 0; o.y = 0; o.z = 0; o.w = 0;
    }
    *(ushort4*)(dst + i) = o;
}

// ---------------------------------------------------------------------------
// GEMM: C(M,N) = A(M,K) @ W(N,K)^T + bias. A,W bf16 (W pre-padded to 128-row
// multiples); bias fp32. R2-verified register staging, [128][40] padded LDS.
// MODE 0: bf16 row-major  MODE 1: qk-pack (flat/192 head split)
// MODE 2: v TRANSPOSED pack vt[b,h,d,s]  MODE 3: fp32 row-major
// ---------------------------------------------------------------------------
template<int MODE>
__global__ __launch_bounds__(256)
void gemm_bf16(const uint16_t* __restrict__ A, const uint16_t* __restrict__ W,
               const float* __restrict__ bias, void* __restrict__ Out,
               int M, int N, int K)
{
    __shared__ uint16_t Alds[128][40];
    __shared__ uint16_t Blds[128][40];

    const int tid  = threadIdx.x;
    const int lane = tid & 63;
    const int wave = tid >> 6;
    const int wm   = wave >> 1;
    const int wn   = wave & 1;
    const int m0   = blockIdx.y << 7;
    const int n0   = blockIdx.x << 7;

    f32x4 acc[4][4];
    #pragma unroll
    for (int i = 0; i < 4; ++i)
        #pragma unroll
        for (int j = 0; j < 4; ++j)
            acc[i][j] = (f32x4){0.f, 0.f, 0.f, 0.f};

    const int rsel = lane & 15;
    const int ksel = (lane >> 4) << 3;

    const int nK = K >> 5;
    for (int kt = 0; kt < nK; ++kt) {
        const int k0 = kt << 5;
        __syncthreads();
        // stage A tile (128 x 32): 1024 ushort4 chunks, 256 threads x 4
        #pragma unroll
        for (int j = 0; j < 4; ++j) {
            int c   = tid + j * 256;
            int row = c >> 3;
            int col = (c & 7) << 2;
            *(ushort4*)&Alds[row][col] = *(const ushort4*)(A + (size_t)(m0 + row) * K + k0 + col);
        }
        // stage B tile (128 x 32) from W (pre-padded rows)
        #pragma unroll
        for (int j = 0; j < 4; ++j) {
            int c   = tid + j * 256;
            int row = c >> 3;
            int col = (c & 7) << 2;
            *(ushort4*)&Blds[row][col] = *(const ushort4*)(W + (size_t)(n0 + row) * K + k0 + col);
        }
        __syncthreads();

        bf16x8 af[4], bfr[4];
        #pragma unroll
        for (int i = 0; i < 4; ++i)
            af[i] = *(const bf16x8*)&Alds[(wm << 6) + (i << 4) + rsel][ksel];
        #pragma unroll
        for (int j = 0; j < 4; ++j)
            bfr[j] = *(const bf16x8*)&Blds[(wn << 6) + (j << 4) + rsel][ksel];

        #pragma unroll
        for (int i = 0; i < 4; ++i)
            #pragma unroll
            for (int j = 0; j < 4; ++j)
                acc[i][j] = __builtin_amdgcn_mfma_f32_16x16x32_bf16(af[i], bfr[j], acc[i][j], 0, 0, 0);
    }

    // epilogue: D lane map: col = lane&15, row = 4*(lane>>4)+r
    const int col = lane & 15;
    const int rg  = lane >> 4;
    #pragma unroll
    for (int i = 0; i < 4; ++i) {
        #pragma unroll
        for (int j = 0; j < 4; ++j) {
            int n = n0 + (wn << 6) + (j << 4) + col;
            if (n >= N) continue;
            float bv = bias[n];
            float v[4];
            #pragma unroll
            for (int r = 0; r < 4; ++r) v[r] = acc[i][j][r] + bv;
            int mbase = m0 + (wm << 6) + (i << 4) + (rg << 2);
            if (MODE == 0) {
                #pragma unroll
                for (int r = 0; r < 4; ++r)
                    ((uint16_t*)Out)[(size_t)(mbase + r) * N + n] = f2bf(v[r]);
            } else if (MODE == 1) {
                int hh = n / 192, d = n - hh * 192;
                int b = mbase >> 11, s = mbase & 2047;
                uint16_t* o = (uint16_t*)Out + (((size_t)(b * 16 + hh) * 2048 + s) * 192) + d;
                #pragma unroll
                for (int r = 0; r < 4; ++r) o[r * 192] = f2bf(v[r]);
            } else if (MODE == 2) {
                int hh = n >> 7, d = n & 127;
                int b = mbase >> 11, s = mbase & 2047;
                ushort4 o;
                o.x = f2bf(v[0]); o.y = f2bf(v[1]); o.z = f2bf(v[2]); o.w = f2bf(v[3]);
                *(ushort4*)&((uint16_t*)Out)[(((size_t)(b * 16 + hh) * 128 + d) * 2048) + s] = o;
            } else {
                #pragma unroll
                for (int r = 0; r < 4; ++r)
                    ((float*)Out)[(size_t)(mbase + r) * N + n] = v[r];
            }
        }
    }
}

// ---------------------------------------------------------------------------
// RoPE kernels (unchanged, verified)
// ---------------------------------------------------------------------------
__global__ __launch_bounds__(256)
void rope_q_kernel(const uint16_t* __restrict__ raw, const float* __restrict__ fc,
                   const float* __restrict__ fs, uint16_t* __restrict__ qp)
{
    int gid = blockIdx.x * 256 + threadIdx.x;
    int m = gid >> 10, n = gid & 1023;
    int hh = n >> 6, d = n & 63;
    int b = m >> 11, s = m & 2047;
    float x  = bf2f(raw[(size_t)m * 1024 + n]);
    float xo = bf2f(raw[(size_t)m * 1024 + hh * 64 + ((d < 32) ? d + 32 : d - 32)]);
    float rot = (d < 32) ? -xo : xo;
    float v = x * fc[s * 64 + d] + rot * fs[s * 64 + d];
    int f = 2048 + n;
    int head = f / 192, dq = f - head * 192;
    qp[(((size_t)(b * 16 + head) * 2048 + s) * 192) + dq] = f2bf(v);
}

__global__ __launch_bounds__(256)
void rope_k_kernel(const uint16_t* __restrict__ raw, const float* __restrict__ fc,
                   const float* __restrict__ fs, uint16_t* __restrict__ kp)
{
    int gid = blockIdx.x * 256 + threadIdx.x;
    int m = gid >> 6, d = gid & 63;
    int b = m >> 11, s = m & 2047;
    float x  = bf2f(raw[(size_t)m * 64 + d]);
    float xo = bf2f(raw[(size_t)m * 64 + ((d < 32) ? d + 32 : d - 32)]);
    float rot = (d < 32) ? -xo : xo;
    uint16_t bv = f2bf(x * fc[s * 64 + d] + rot * fs[s * 64 + d]);
    #pragma unroll
    for (int hh = 0; hh < 16; ++hh) {
        int f = 2048 + hh * 64 + d;
        int head = f / 192, dk = f - head * 192;
        kp[(((size_t)(b * 16 + head) * 2048 + s) * 192) + dk] = bv;
    }
}

// ---------------------------------------------------------------------------
// MFMA flash attention (causal). 4 waves; Q-tile 128 rows (32/wave, 2 x 16-row
// fragments); KV-tile 64. V arrives pre-transposed (vt[b,h,d,s]) -> staged
// row-major into Vs[d][kv]. barrier -> stage -> barrier -> compute.
// ---------------------------------------------------------------------------
__global__ __launch_bounds__(256)
void attn_mfma2(const uint16_t* __restrict__ qp, const uint16_t* __restrict__ kp,
                const uint16_t* __restrict__ vt, uint16_t* __restrict__ yf)
{
    __shared__ uint16_t Ks[64][200];
    __shared__ uint16_t Vs[128][72];
    __shared__ uint16_t Ps[4][32][72];

    const int tid  = threadIdx.x;
    const int lane = tid & 63;
    const int w    = tid >> 6;
    const int g    = lane >> 4;
    const int li   = lane & 15;
    const int bh   = blockIdx.y;
    const int b    = bh >> 4;
    const int h    = bh & 15;
    const int qt   = gridDim.x - 1 - blockIdx.x;   // heavy tiles dispatch first
    const int q0   = qt << 7;

    const size_t qkb = (size_t)bh * 2048 * 192;
    const size_t vtb = (size_t)bh * 128 * 2048;

    // Q fragments: wave owns rows q0+w*32 .. +31 (two 16-row tiles)
    bf16x8 qf[2][6];
    #pragma unroll
    for (int rt = 0; rt < 2; ++rt)
        #pragma unroll
        for (int kk = 0; kk < 6; ++kk)
            qf[rt][kk] = *(const bf16x8*)(qp + qkb +
                (size_t)(q0 + (w << 5) + (rt << 4) + li) * 192 + kk * 32 + (g << 3));

    float mst[2][4], lst[2][4];
    f32x4 oacc[2][8];
    #pragma unroll
    for (int rt = 0; rt < 2; ++rt) {
        #pragma unroll
        for (int r = 0; r < 4; ++r) { mst[rt][r] = -__builtin_inff(); lst[rt][r] = 0.f; }
        #pragma unroll
        for (int ct = 0; ct < 8; ++ct) oacc[rt][ct] = (f32x4){0.f, 0.f, 0.f, 0.f};
    }
    const float scl = 0.07216878364870323f * 1.4426950408889634f;  // 1/sqrt(192)*log2e

    const int ntiles = (qt << 1) + 2;
    for (int t = 0; t < ntiles; ++t) {
        const int j0 = t << 6;
        __syncthreads();
        // stage K tile 64x192
        #pragma unroll
        for (int p = 0; p < 6; ++p) {
            int idx = tid + p * 256;
            int r = idx / 24, c8 = (idx - r * 24) << 3;
            *(bf16x8*)&Ks[r][c8] = *(const bf16x8*)(kp + qkb + (size_t)(j0 + r) * 192 + c8);
        }
        // stage V tile: Vs[d][kv] from vt[b,h,d,s]
        #pragma unroll
        for (int p = 0; p < 8; ++p) {
            int idx = tid + p * 256;
            int r = idx >> 4, c4 = (idx & 15) << 2;
            *(ushort4*)&Vs[r][c4] = *(const ushort4*)(vt + vtb + (size_t)r * 2048 + j0 + c4);
        }
        __syncthreads();

        // S = Q K^T
        f32x4 sacc[2][4];
        #pragma unroll
        for (int rt = 0; rt < 2; ++rt)
            #pragma unroll
            for (int c = 0; c < 4; ++c) sacc[rt][c] = (f32x4){0.f, 0.f, 0.f, 0.f};
        #pragma unroll
        for (int c = 0; c < 4; ++c) {
            #pragma unroll
            for (int kk = 0; kk < 6; ++kk) {
                bf16x8 kf = *(const bf16x8*)&Ks[(c << 4) + li][kk * 32 + (g << 3)];
                sacc[0][c] = __builtin_amdgcn_mfma_f32_16x16x32_bf16(qf[0][kk], kf, sacc[0][c], 0, 0, 0);
                sacc[1][c] = __builtin_amdgcn_mfma_f32_16x16x32_bf16(qf[1][kk], kf, sacc[1][c], 0, 0, 0);
            }
        }

        // online softmax; rows live in 16-lane groups (all 64 lanes active)
        float corr[2][4];
        #pragma unroll
        for (int rt = 0; rt < 2; ++rt) {
            #pragma unroll
            for (int r = 0; r < 4; ++r) {
                const int rq = q0 + (w << 5) + (rt << 4) + (g << 2) + r;
                float sv[4];
                float mx = -__builtin_inff();
                #pragma unroll
                for (int c = 0; c < 4; ++c) {
                    int colk = j0 + (c << 4) + li;
                    sv[c] = (colk <= rq) ? sacc[rt][c][r] * scl : -__builtin_inff();
                    mx = fmaxf(mx, sv[c]);
                }
                #pragma unroll
                for (int off = 8; off >= 1; off >>= 1) mx = fmaxf(mx, __shfl_xor(mx, off, 64));
                float mnew = fmaxf(mst[rt][r], mx);
                corr[rt][r] = exp2f(mst[rt][r] - mnew);
                mst[rt][r] = mnew;
                float psum = 0.f;
                #pragma unroll
                for (int c = 0; c < 4; ++c) {
                    float p = exp2f(sv[c] - mnew);
                    psum += p;
                    Ps[w][(rt << 4) + (g << 2) + r][(c << 4) + li] = f2bf(p);
                }
                #pragma unroll
                for (int off = 8; off >= 1; off >>= 1) psum += __shfl_xor(psum, off, 64);
                lst[rt][r] = lst[rt][r] * corr[rt][r] + psum;
            }
        }

        // O = O*corr + P V
        #pragma unroll
        for (int rt = 0; rt < 2; ++rt)
            #pragma unroll
            for (int ct = 0; ct < 8; ++ct)
                #pragma unroll
                for (int r = 0; r < 4; ++r) oacc[rt][ct][r] *= corr[rt][r];

        bf16x8 pf0[2], pf1[2];
        #pragma unroll
        for (int rt = 0; rt < 2; ++rt) {
            pf0[rt] = *(const bf16x8*)&Ps[w][(rt << 4) + li][(g << 3)];
            pf1[rt] = *(const bf16x8*)&Ps[w][(rt << 4) + li][32 + (g << 3)];
        }
        #pragma unroll
        for (int ct = 0; ct < 8; ++ct) {
            bf16x8 vf0 = *(const bf16x8*)&Vs[(ct << 4) + li][(g << 3)];
            bf16x8 vf1 = *(const bf16x8*)&Vs[(ct << 4) + li][32 + (g << 3)];
            #pragma unroll
            for (int rt = 0; rt < 2; ++rt) {
                oacc[rt][ct] = __builtin_amdgcn_mfma_f32_16x16x32_bf16(pf0[rt], vf0, oacc[rt][ct], 0, 0, 0);
                oacc[rt][ct] = __builtin_amdgcn_mfma_f32_16x16x32_bf16(pf1[rt], vf1, oacc[rt][ct], 0, 0, 0);
            }
        }
    }

    #pragma unroll
    for (int rt = 0; rt < 2; ++rt) {
        #pragma unroll
        for (int r = 0; r < 4; ++r) {
            float inv = 1.f / lst[rt][r];
            int rq = q0 + (w << 5) + (rt << 4) + (g << 2) + r;
            size_t obase = ((size_t)(b * 2048 + rq) * 2048) + h * 128;
            #pragma unroll
            for (int ct = 0; ct < 8; ++ct)
                yf[obase + (ct << 4) + li] = f2bf(oacc[rt][ct][r] * inv);
        }
    }
}

// ---------------------------------------------------------------------------
extern "C" void kernel_launch(void* const* d_in, const int* in_sizes, int n_in,
                              void* d_out, int out_size, void* d_ws, size_t ws_size,
                              hipStream_t stream)
{
    const float* x     = (const float*)d_in[0];
    const float* fcos  = (const float*)d_in[1];
    const float* fsin  = (const float*)d_in[2];
    const float* W_dq  = (const float*)d_in[3];
    const float* b_dq  = (const float*)d_in[4];
    const float* W_uq  = (const float*)d_in[5];
    const float* b_uq  = (const float*)d_in[6];
    const float* W_qr  = (const float*)d_in[7];
    const float* b_qr  = (const float*)d_in[8];
    const float* W_dkv = (const float*)d_in[9];
    const float* b_dkv = (const float*)d_in[10];
    const float* W_uk  = (const float*)d_in[11];
    const float* b_uk  = (const float*)d_in[12];
    const float* W_uv  = (const float*)d_in[13];
    const float* b_uv  = (const float*)d_in[14];
    const float* W_kr  = (const float*)d_in[15];
    const float* b_kr  = (const float*)d_in[16];
    const float* W_out = (const float*)d_in[17];
    const float* b_out = (const float*)d_in[18];

    char* ws = (char*)d_ws;
    // Repacked layout, max byte = 103,284,736.
    // Aliases (all justified by launch order below):
    //   vtb (27,262,976..44,040,192) over Wdq_b,Wuq_b,Wqr_b,Wkr_b,c_q-head — dead after rope_q
    //   kp  (44,040,192..69,206,016) over c_q-tail,qr_raw — dead after rope_q
    //   yf = xb — xb dead after the three down-projections
    uint16_t* xb     = (uint16_t*)(ws + 0);              // 4096x2048        [end 16,777,216]
    uint16_t* Wuk_b  = (uint16_t*)(ws + 16777216);       // 2048x512         [end 18,874,368]
    uint16_t* Wuv_b  = (uint16_t*)(ws + 18874368);       // 2048x512         [end 20,971,520]
    uint16_t* c_kv   = (uint16_t*)(ws + 20971520);       // 4096x512         [end 25,165,824]
    uint16_t* Wdkv_b = (uint16_t*)(ws + 25165824);       // 512x2048         [end 27,262,976]
    uint16_t* Wdq_b  = (uint16_t*)(ws + 27262976);       // 1536x2048        [end 33,554,432]
    uint16_t* Wuq_b  = (uint16_t*)(ws + 33554432);       // 2048x1536        [end 39,845,888]
    uint16_t* Wqr_b  = (uint16_t*)(ws + 39845888);       // 1024x1536        [end 42,991,616]
    uint16_t* Wkr_b  = (uint16_t*)(ws + 42991616);       // 128x2048 pad     [end 43,515,904]
    uint16_t* c_q    = (uint16_t*)(ws + 43515904);       // 4096x1536        [end 56,098,816]
    uint16_t* qr_raw = (uint16_t*)(ws + 56098816);       // 4096x1024        [end 64,487,424]
    uint16_t* vtb    = (uint16_t*)(ws + 27262976);       // (2,16,128,2048)  [end 44,040,192] ALIAS
    uint16_t* kp     = (uint16_t*)(ws + 44040192);       // (2,16,2048,192)  [end 69,206,016] ALIAS
    uint16_t* qp     = (uint16_t*)(ws + 69206016);       // (2,16,2048,192)  [end 94,371,840]
    uint16_t* kr_raw = (uint16_t*)(ws + 94371840);       // 4096x64          [end 94,896,128]
    uint16_t* Wout_b = (uint16_t*)(ws + 94896128);       // 2048x2048        [end 103,284,736]
    uint16_t* yf     = xb;                               // 4096x2048 ALIAS

    dim3 blk(256);
    // bf16 conversions -- element counts: full tensor sizes (R3-R5 bug: W_uk/W_uv
    // are 2048x512 = 1,048,576 elems; was wrongly 524,288 -> poison weights for
    // heads 8-15).
    conv_kernel<<<dim3(8192), blk, 0, stream>>>(x,     xb,     8388608, 8388608);
    conv_kernel<<<dim3(3072), blk, 0, stream>>>(W_dq,  Wdq_b,  3145728, 3145728);
    conv_kernel<<<dim3(1024), blk, 0, stream>>>(W_dkv, Wdkv_b, 1048576, 1048576);
    conv_kernel<<<dim3( 256), blk, 0, stream>>>(W_kr,  Wkr_b,   131072,  262144);
    conv_kernel<<<dim3(3072), blk, 0, stream>>>(W_uq,  Wuq_b,  3145728, 3145728);
    conv_kernel<<<dim3(1536), blk, 0, stream>>>(W_qr,  Wqr_b,  1572864, 1572864);
    conv_kernel<<<dim3(1024), blk, 0, stream>>>(W_uk,  Wuk_b,  1048576, 1048576);
    conv_kernel<<<dim3(1024), blk, 0, stream>>>(W_uv,  Wuv_b,  1048576, 1048576);
    conv_kernel<<<dim3(4096), blk, 0, stream>>>(W_out, Wout_b, 4194304, 4194304);

    // projections
    gemm_bf16<0><<<dim3(12, 32), blk, 0, stream>>>(xb,   Wdq_b,  b_dq,  c_q,    4096, 1536, 2048);
    gemm_bf16<0><<<dim3( 4, 32), blk, 0, stream>>>(xb,   Wdkv_b, b_dkv, c_kv,   4096,  512, 2048);
    gemm_bf16<0><<<dim3( 1, 32), blk, 0, stream>>>(xb,   Wkr_b,  b_kr,  kr_raw, 4096,   64, 2048);
    gemm_bf16<1><<<dim3(16, 32), blk, 0, stream>>>(c_q,  Wuq_b,  b_uq,  qp,     4096, 2048, 1536);
    gemm_bf16<0><<<dim3( 8, 32), blk, 0, stream>>>(c_q,  Wqr_b,  b_qr,  qr_raw, 4096, 1024, 1536);
    rope_q_kernel<<<dim3(16384), blk, 0, stream>>>(qr_raw, fcos, fsin, qp);
    // --- c_q, qr_raw, Wdq_b, Wuq_b, Wqr_b, Wkr_b now dead ---
    gemm_bf16<1><<<dim3(16, 32), blk, 0, stream>>>(c_kv, Wuk_b,  b_uk,  kp,     4096, 2048,  512);
    rope_k_kernel<<<dim3(1024),  blk, 0, stream>>>(kr_raw, fcos, fsin, kp);
    // --- kr_raw now dead ---
    gemm_bf16<2><<<dim3(16, 32), blk, 0, stream>>>(c_kv, Wuv_b,  b_uv,  vtb,    4096, 2048,  512);
    // --- c_kv now dead ---

    // attention (xb dead -> yf alias safe)
    attn_mfma2<<<dim3(16, 32), blk, 0, stream>>>(qp, kp, vtb, yf);

    // output projection
    gemm_bf16<3><<<dim3(16, 32), blk, 0, stream>>>(yf, Wout_b, b_out, d_out, 4096, 2048, 2048);
}

// Round 7
// 629.722 us; speedup vs baseline: 26.1045x; 1.0784x over previous
//
#include <hip/hip_runtime.h>
#include <hip/hip_bf16.h>
#include <stdint.h>

// MLA forward, B=2 S=2048 DIM=2048 NH=16 HD=128 HDR=64 DCKV=512 DCQ=1536
// Round 7: reintroduce the R3 mechanisms (validated correct by R3==R4 bit-
// identical outputs; R3-R5 failures were a conv element-count bug, fixed R6):
//   - GEMM: global_load_lds width-16 staging (m97 structure)
//   - attn: async-stage split (T14) + s_setprio around MFMA (T5)
//
// Reference reshape quirk: q = concat([uq(2048), rq(1024)]).reshape(...,16,192)
// -> head h owns FLAT dims [192h,192h+192) of the concat (same for k).

typedef __bf16 bf16x8 __attribute__((ext_vector_type(8)));
typedef float  f32x4  __attribute__((ext_vector_type(4)));

__device__ __forceinline__ uint16_t f2bf(float f) {
    uint32_t u = __builtin_bit_cast(uint32_t, f);
    u = (u + 0x7FFFu + ((u >> 16) & 1u)) >> 16;
    return (uint16_t)u;
}
__device__ __forceinline__ float bf2f(uint16_t h) {
    uint32_t u = ((uint32_t)h) << 16;
    return __builtin_bit_cast(float, u);
}

typedef __attribute__((address_space(3))) uint32_t lds_u32_t;
typedef const __attribute__((address_space(1))) uint32_t glb_u32_t;

// async global->LDS, 16B per lane. LDS dest = wave-uniform base + lane*16.
__device__ __forceinline__ void gld16(const void* g, const void* l) {
    __builtin_amdgcn_global_load_lds((glb_u32_t*)(uintptr_t)g,
                                     (lds_u32_t*)(uint32_t)(uintptr_t)l, 16, 0, 0);
}

// ---------------------------------------------------------------------------
// fp32 -> bf16 conversion (zero-fills dst beyond n_src, for padded W_kr)
// ---------------------------------------------------------------------------
__global__ __launch_bounds__(256)
void conv_kernel(const float* __restrict__ src, uint16_t* __restrict__ dst,
                 int n_src, int n_dst)
{
    int i = (blockIdx.x * 256 + threadIdx.x) << 2;
    if (i >= n_dst) return;
    ushort4 o;
    if (i < n_src) {
        float4 v = *(const float4*)(src + i);
        o.x = f2bf(v.x); o.y = f2bf(v.y); o.z = f2bf(v.z); o.w = f2bf(v.w);
    } else {
        o.x = 0; o.y = 0; o.z = 0; o.w = 0;
    }
    *(ushort4*)(dst + i) = o;
}

// ---------------------------------------------------------------------------
// GEMM: C(M,N) = A(M,K) @ W(N,K)^T + bias. A,W bf16 (W pre-padded to 128-row
// multiples); bias fp32. m97 structure: 128x128 tile, BK=32,
// global_load_lds dwordx4 staging, 2 barriers per K-step.
// MODE 0: bf16 row-major  MODE 1: qk-pack (flat/192 head split)
// MODE 2: v TRANSPOSED pack vt[b,h,d,s]  MODE 3: fp32 row-major
// ---------------------------------------------------------------------------
template<int MODE>
__global__ __launch_bounds__(256, 2)
void gemm_bf16(const uint16_t* __restrict__ A, const uint16_t* __restrict__ W,
               const float* __restrict__ bias, void* __restrict__ Out,
               int M, int N, int K)
{
    __shared__ __align__(16) uint16_t Alds[128 * 32];
    __shared__ __align__(16) uint16_t Blds[128 * 32];

    const int tid  = threadIdx.x;
    const int lane = tid & 63;
    const int wave = tid >> 6;
    const int wm   = wave >> 1;
    const int wn   = wave & 1;
    const int m0   = blockIdx.y << 7;
    const int n0   = blockIdx.x << 7;

    f32x4 acc[4][4];
    #pragma unroll
    for (int i = 0; i < 4; ++i)
        #pragma unroll
        for (int j = 0; j < 4; ++j)
            acc[i][j] = (f32x4){0.f, 0.f, 0.f, 0.f};

    // staging map: per wave 2 gld16 per matrix; lane covers
    // row = wave*32 + i*16 + (lane>>2), 16B chunk = lane&3; LDS linear row-major.
    const int r0 = (wave << 5) + (lane >> 2);
    const int ck = (lane & 3) << 3;
    const uint16_t* gA0 = A + (size_t)(m0 + r0) * K + ck;
    const uint16_t* gA1 = gA0 + (size_t)16 * K;
    const uint16_t* gB0 = W + (size_t)(n0 + r0) * K + ck;
    const uint16_t* gB1 = gB0 + (size_t)16 * K;
    const uint16_t* lA0 = Alds + (wave << 10);
    const uint16_t* lA1 = lA0 + 512;
    const uint16_t* lB0 = Blds + (wave << 10);
    const uint16_t* lB1 = lB0 + 512;

    const int rsel = lane & 15;
    const int g8   = (lane >> 4) << 3;

    const int nK = K >> 5;
    for (int kt = 0; kt < nK; ++kt) {
        __syncthreads();
        gld16(gA0, lA0); gld16(gA1, lA1);
        gld16(gB0, lB0); gld16(gB1, lB1);
        gA0 += 32; gA1 += 32; gB0 += 32; gB1 += 32;
        __syncthreads();

        bf16x8 af[4], bfr[4];
        #pragma unroll
        for (int i = 0; i < 4; ++i)
            af[i] = *(const bf16x8*)&Alds[(((wm << 6) + (i << 4) + rsel) << 5) + g8];
        #pragma unroll
        for (int j = 0; j < 4; ++j)
            bfr[j] = *(const bf16x8*)&Blds[(((wn << 6) + (j << 4) + rsel) << 5) + g8];

        #pragma unroll
        for (int i = 0; i < 4; ++i)
            #pragma unroll
            for (int j = 0; j < 4; ++j)
                acc[i][j] = __builtin_amdgcn_mfma_f32_16x16x32_bf16(af[i], bfr[j], acc[i][j], 0, 0, 0);
    }

    // epilogue: D lane map: col = lane&15, row = 4*(lane>>4)+r
    const int col = lane & 15;
    const int rg  = lane >> 4;
    #pragma unroll
    for (int i = 0; i < 4; ++i) {
        #pragma unroll
        for (int j = 0; j < 4; ++j) {
            int n = n0 + (wn << 6) + (j << 4) + col;
            if (n >= N) continue;
            float bv = bias[n];
            float v[4];
            #pragma unroll
            for (int r = 0; r < 4; ++r) v[r] = acc[i][j][r] + bv;
            int mbase = m0 + (wm << 6) + (i << 4) + (rg << 2);
            if (MODE == 0) {
                #pragma unroll
                for (int r = 0; r < 4; ++r)
                    ((uint16_t*)Out)[(size_t)(mbase + r) * N + n] = f2bf(v[r]);
            } else if (MODE == 1) {
                int hh = n / 192, d = n - hh * 192;
                int b = mbase >> 11, s = mbase & 2047;
                uint16_t* o = (uint16_t*)Out + (((size_t)(b * 16 + hh) * 2048 + s) * 192) + d;
                #pragma unroll
                for (int r = 0; r < 4; ++r) o[r * 192] = f2bf(v[r]);
            } else if (MODE == 2) {
                int hh = n >> 7, d = n & 127;
                int b = mbase >> 11, s = mbase & 2047;
                ushort4 o;
                o.x = f2bf(v[0]); o.y = f2bf(v[1]); o.z = f2bf(v[2]); o.w = f2bf(v[3]);
                *(ushort4*)&((uint16_t*)Out)[(((size_t)(b * 16 + hh) * 128 + d) * 2048) + s] = o;
            } else {
                #pragma unroll
                for (int r = 0; r < 4; ++r)
                    ((float*)Out)[(size_t)(mbase + r) * N + n] = v[r];
            }
        }
    }
}

// ---------------------------------------------------------------------------
// RoPE kernels (unchanged, verified)
// ---------------------------------------------------------------------------
__global__ __launch_bounds__(256)
void rope_q_kernel(const uint16_t* __restrict__ raw, const float* __restrict__ fc,
                   const float* __restrict__ fs, uint16_t* __restrict__ qp)
{
    int gid = blockIdx.x * 256 + threadIdx.x;
    int m = gid >> 10, n = gid & 1023;
    int hh = n >> 6, d = n & 63;
    int b = m >> 11, s = m & 2047;
    float x  = bf2f(raw[(size_t)m * 1024 + n]);
    float xo = bf2f(raw[(size_t)m * 1024 + hh * 64 + ((d < 32) ? d + 32 : d - 32)]);
    float rot = (d < 32) ? -xo : xo;
    float v = x * fc[s * 64 + d] + rot * fs[s * 64 + d];
    int f = 2048 + n;
    int head = f / 192, dq = f - head * 192;
    qp[(((size_t)(b * 16 + head) * 2048 + s) * 192) + dq] = f2bf(v);
}

__global__ __launch_bounds__(256)
void rope_k_kernel(const uint16_t* __restrict__ raw, const float* __restrict__ fc,
                   const float* __restrict__ fs, uint16_t* __restrict__ kp)
{
    int gid = blockIdx.x * 256 + threadIdx.x;
    int m = gid >> 6, d = gid & 63;
    int b = m >> 11, s = m & 2047;
    float x  = bf2f(raw[(size_t)m * 64 + d]);
    float xo = bf2f(raw[(size_t)m * 64 + ((d < 32) ? d + 32 : d - 32)]);
    float rot = (d < 32) ? -xo : xo;
    uint16_t bv = f2bf(x * fc[s * 64 + d] + rot * fs[s * 64 + d]);
    #pragma unroll
    for (int hh = 0; hh < 16; ++hh) {
        int f = 2048 + hh * 64 + d;
        int head = f / 192, dk = f - head * 192;
        kp[(((size_t)(b * 16 + head) * 2048 + s) * 192) + dk] = bv;
    }
}

// ---------------------------------------------------------------------------
// MFMA flash attention (causal). 4 waves; Q-tile 128 rows (32/wave); KV=64.
// V pre-transposed (vt[b,h,d,s]). T14 async-stage: K loads before QK, V loads
// after QK, LDS writes after the compute barrier. T5 setprio around MFMA.
// ---------------------------------------------------------------------------
__global__ __launch_bounds__(256, 2)
void attn_mfma2(const uint16_t* __restrict__ qp, const uint16_t* __restrict__ kp,
                const uint16_t* __restrict__ vt, uint16_t* __restrict__ yf)
{
    __shared__ __align__(16) uint16_t Ks[64][200];
    __shared__ __align__(16) uint16_t Vs[128][72];
    __shared__ __align__(16) uint16_t Ps[4][32][72];

    const int tid  = threadIdx.x;
    const int lane = tid & 63;
    const int w    = tid >> 6;
    const int g    = lane >> 4;
    const int li   = lane & 15;
    const int bh   = blockIdx.y;
    const int b    = bh >> 4;
    const int h    = bh & 15;
    const int qt   = gridDim.x - 1 - blockIdx.x;   // heavy tiles dispatch first
    const int q0   = qt << 7;

    const size_t qkb = (size_t)bh * 2048 * 192;
    const size_t vtb = (size_t)bh * 128 * 2048;

    // Q fragments: wave owns rows q0+w*32 .. +31 (two 16-row tiles)
    bf16x8 qf[2][6];
    #pragma unroll
    for (int rt = 0; rt < 2; ++rt)
        #pragma unroll
        for (int kk = 0; kk < 6; ++kk)
            qf[rt][kk] = *(const bf16x8*)(qp + qkb +
                (size_t)(q0 + (w << 5) + (rt << 4) + li) * 192 + kk * 32 + (g << 3));

    float mst[2][4], lst[2][4];
    f32x4 oacc[2][8];
    #pragma unroll
    for (int rt = 0; rt < 2; ++rt) {
        #pragma unroll
        for (int r = 0; r < 4; ++r) { mst[rt][r] = -__builtin_inff(); lst[rt][r] = 0.f; }
        #pragma unroll
        for (int ct = 0; ct < 8; ++ct) oacc[rt][ct] = (f32x4){0.f, 0.f, 0.f, 0.f};
    }
    const float scl = 0.07216878364870323f * 1.4426950408889634f;  // 1/sqrt(192)*log2e

    // staging maps
    int krp[6], kcp[6], vrp[8], vcp[8];
    #pragma unroll
    for (int p = 0; p < 6; ++p) {
        int idx = tid + p * 256;
        krp[p] = idx / 24; kcp[p] = (idx - krp[p] * 24) << 3;
    }
    #pragma unroll
    for (int p = 0; p < 8; ++p) {
        int idx = tid + p * 256;
        vrp[p] = idx >> 4; vcp[p] = (idx & 15) << 2;
    }

    bf16x8  kreg[6];
    ushort4 vreg[8];

    // prologue: stage tile 0
    #pragma unroll
    for (int p = 0; p < 6; ++p)
        kreg[p] = *(const bf16x8*)(kp + qkb + (size_t)krp[p] * 192 + kcp[p]);
    #pragma unroll
    for (int p = 0; p < 8; ++p)
        vreg[p] = *(const ushort4*)(vt + vtb + (size_t)vrp[p] * 2048 + vcp[p]);
    #pragma unroll
    for (int p = 0; p < 6; ++p) *(bf16x8*)&Ks[krp[p]][kcp[p]] = kreg[p];
    #pragma unroll
    for (int p = 0; p < 8; ++p) *(ushort4*)&Vs[vrp[p]][vcp[p]] = vreg[p];
    __syncthreads();

    const int ntiles = (qt << 1) + 2;
    for (int t = 0; t < ntiles; ++t) {
        const int j0   = t << 6;
        const int j0n  = j0 + 64;
        const bool pre = (t + 1 < ntiles);

        // issue next K loads (cover: QK + softmax + PV)
        if (pre) {
            #pragma unroll
            for (int p = 0; p < 6; ++p)
                kreg[p] = *(const bf16x8*)(kp + qkb + (size_t)(j0n + krp[p]) * 192 + kcp[p]);
        }

        // S = Q K^T
        f32x4 sacc[2][4];
        #pragma unroll
        for (int rt = 0; rt < 2; ++rt)
            #pragma unroll
            for (int c = 0; c < 4; ++c) sacc[rt][c] = (f32x4){0.f, 0.f, 0.f, 0.f};
        __builtin_amdgcn_s_setprio(1);
        #pragma unroll
        for (int c = 0; c < 4; ++c) {
            #pragma unroll
            for (int kk = 0; kk < 6; ++kk) {
                bf16x8 kf = *(const bf16x8*)&Ks[(c << 4) + li][kk * 32 + (g << 3)];
                sacc[0][c] = __builtin_amdgcn_mfma_f32_16x16x32_bf16(qf[0][kk], kf, sacc[0][c], 0, 0, 0);
                sacc[1][c] = __builtin_amdgcn_mfma_f32_16x16x32_bf16(qf[1][kk], kf, sacc[1][c], 0, 0, 0);
            }
        }
        __builtin_amdgcn_s_setprio(0);

        // issue next V loads (cover: softmax + PV)
        if (pre) {
            #pragma unroll
            for (int p = 0; p < 8; ++p)
                vreg[p] = *(const ushort4*)(vt + vtb + (size_t)vrp[p] * 2048 + j0n + vcp[p]);
        }

        // online softmax; rows live in 16-lane groups (all 64 lanes active)
        float corr[2][4];
        #pragma unroll
        for (int rt = 0; rt < 2; ++rt) {
            #pragma unroll
            for (int r = 0; r < 4; ++r) {
                const int rq = q0 + (w << 5) + (rt << 4) + (g << 2) + r;
                float sv[4];
                float mx = -__builtin_inff();
                #pragma unroll
                for (int c = 0; c < 4; ++c) {
                    int colk = j0 + (c << 4) + li;
                    sv[c] = (colk <= rq) ? sacc[rt][c][r] * scl : -__builtin_inff();
                    mx = fmaxf(mx, sv[c]);
                }
                #pragma unroll
                for (int off = 8; off >= 1; off >>= 1) mx = fmaxf(mx, __shfl_xor(mx, off, 64));
                float mnew = fmaxf(mst[rt][r], mx);
                corr[rt][r] = exp2f(mst[rt][r] - mnew);
                mst[rt][r] = mnew;
                float psum = 0.f;
                #pragma unroll
                for (int c = 0; c < 4; ++c) {
                    float p = exp2f(sv[c] - mnew);
                    psum += p;
                    Ps[w][(rt << 4) + (g << 2) + r][(c << 4) + li] = f2bf(p);
                }
                #pragma unroll
                for (int off = 8; off >= 1; off >>= 1) psum += __shfl_xor(psum, off, 64);
                lst[rt][r] = lst[rt][r] * corr[rt][r] + psum;
            }
        }

        // O = O*corr + P V
        #pragma unroll
        for (int rt = 0; rt < 2; ++rt)
            #pragma unroll
            for (int ct = 0; ct < 8; ++ct)
                #pragma unroll
                for (int r = 0; r < 4; ++r) oacc[rt][ct][r] *= corr[rt][r];

        bf16x8 pf0[2], pf1[2];
        #pragma unroll
        for (int rt = 0; rt < 2; ++rt) {
            pf0[rt] = *(const bf16x8*)&Ps[w][(rt << 4) + li][(g << 3)];
            pf1[rt] = *(const bf16x8*)&Ps[w][(rt << 4) + li][32 + (g << 3)];
        }
        __builtin_amdgcn_s_setprio(1);
        #pragma unroll
        for (int ct = 0; ct < 8; ++ct) {
            bf16x8 vf0 = *(const bf16x8*)&Vs[(ct << 4) + li][(g << 3)];
            bf16x8 vf1 = *(const bf16x8*)&Vs[(ct << 4) + li][32 + (g << 3)];
            #pragma unroll
            for (int rt = 0; rt < 2; ++rt) {
                oacc[rt][ct] = __builtin_amdgcn_mfma_f32_16x16x32_bf16(pf0[rt], vf0, oacc[rt][ct], 0, 0, 0);
                oacc[rt][ct] = __builtin_amdgcn_mfma_f32_16x16x32_bf16(pf1[rt], vf1, oacc[rt][ct], 0, 0, 0);
            }
        }
        __builtin_amdgcn_s_setprio(0);

        __syncthreads();   // everyone done reading Ks/Vs
        if (pre) {
            #pragma unroll
            for (int p = 0; p < 6; ++p) *(bf16x8*)&Ks[krp[p]][kcp[p]] = kreg[p];
            #pragma unroll
            for (int p = 0; p < 8; ++p) *(ushort4*)&Vs[vrp[p]][vcp[p]] = vreg[p];
            __syncthreads();
        }
    }

    #pragma unroll
    for (int rt = 0; rt < 2; ++rt) {
        #pragma unroll
        for (int r = 0; r < 4; ++r) {
            float inv = 1.f / lst[rt][r];
            int rq = q0 + (w << 5) + (rt << 4) + (g << 2) + r;
            size_t obase = ((size_t)(b * 2048 + rq) * 2048) + h * 128;
            #pragma unroll
            for (int ct = 0; ct < 8; ++ct)
                yf[obase + (ct << 4) + li] = f2bf(oacc[rt][ct][r] * inv);
        }
    }
}

// ---------------------------------------------------------------------------
extern "C" void kernel_launch(void* const* d_in, const int* in_sizes, int n_in,
                              void* d_out, int out_size, void* d_ws, size_t ws_size,
                              hipStream_t stream)
{
    const float* x     = (const float*)d_in[0];
    const float* fcos  = (const float*)d_in[1];
    const float* fsin  = (const float*)d_in[2];
    const float* W_dq  = (const float*)d_in[3];
    const float* b_dq  = (const float*)d_in[4];
    const float* W_uq  = (const float*)d_in[5];
    const float* b_uq  = (const float*)d_in[6];
    const float* W_qr  = (const float*)d_in[7];
    const float* b_qr  = (const float*)d_in[8];
    const float* W_dkv = (const float*)d_in[9];
    const float* b_dkv = (const float*)d_in[10];
    const float* W_uk  = (const float*)d_in[11];
    const float* b_uk  = (const float*)d_in[12];
    const float* W_uv  = (const float*)d_in[13];
    const float* b_uv  = (const float*)d_in[14];
    const float* W_kr  = (const float*)d_in[15];
    const float* b_kr  = (const float*)d_in[16];
    const float* W_out = (const float*)d_in[17];
    const float* b_out = (const float*)d_in[18];

    char* ws = (char*)d_ws;
    // Layout (R5/R6-verified), max byte = 103,284,736.
    // Aliases: vtb over {Wdq_b,Wuq_b,Wqr_b,Wkr_b,c_q-head} (dead after rope_q);
    //          kp over {c_q-tail, qr_raw} (dead after rope_q); yf = xb.
    uint16_t* xb     = (uint16_t*)(ws + 0);              // 4096x2048        [end 16,777,216]
    uint16_t* Wuk_b  = (uint16_t*)(ws + 16777216);       // 2048x512         [end 18,874,368]
    uint16_t* Wuv_b  = (uint16_t*)(ws + 18874368);       // 2048x512         [end 20,971,520]
    uint16_t* c_kv   = (uint16_t*)(ws + 20971520);       // 4096x512         [end 25,165,824]
    uint16_t* Wdkv_b = (uint16_t*)(ws + 25165824);       // 512x2048         [end 27,262,976]
    uint16_t* Wdq_b  = (uint16_t*)(ws + 27262976);       // 1536x2048        [end 33,554,432]
    uint16_t* Wuq_b  = (uint16_t*)(ws + 33554432);       // 2048x1536        [end 39,845,888]
    uint16_t* Wqr_b  = (uint16_t*)(ws + 39845888);       // 1024x1536        [end 42,991,616]
    uint16_t* Wkr_b  = (uint16_t*)(ws + 42991616);       // 128x2048 pad     [end 43,515,904]
    uint16_t* c_q    = (uint16_t*)(ws + 43515904);       // 4096x1536        [end 56,098,816]
    uint16_t* qr_raw = (uint16_t*)(ws + 56098816);       // 4096x1024        [end 64,487,424]
    uint16_t* vtb    = (uint16_t*)(ws + 27262976);       // (2,16,128,2048)  [end 44,040,192] ALIAS
    uint16_t* kp     = (uint16_t*)(ws + 44040192);       // (2,16,2048,192)  [end 69,206,016] ALIAS
    uint16_t* qp     = (uint16_t*)(ws + 69206016);       // (2,16,2048,192)  [end 94,371,840]
    uint16_t* kr_raw = (uint16_t*)(ws + 94371840);       // 4096x64          [end 94,896,128]
    uint16_t* Wout_b = (uint16_t*)(ws + 94896128);       // 2048x2048        [end 103,284,736]
    uint16_t* yf     = xb;                               // 4096x2048 ALIAS

    dim3 blk(256);
    // bf16 conversions (full element counts — R3-R5 bug was 524288 here)
    conv_kernel<<<dim3(8192), blk, 0, stream>>>(x,     xb,     8388608, 8388608);
    conv_kernel<<<dim3(3072), blk, 0, stream>>>(W_dq,  Wdq_b,  3145728, 3145728);
    conv_kernel<<<dim3(1024), blk, 0, stream>>>(W_dkv, Wdkv_b, 1048576, 1048576);
    conv_kernel<<<dim3( 256), blk, 0, stream>>>(W_kr,  Wkr_b,   131072,  262144);
    conv_kernel<<<dim3(3072), blk, 0, stream>>>(W_uq,  Wuq_b,  3145728, 3145728);
    conv_kernel<<<dim3(1536), blk, 0, stream>>>(W_qr,  Wqr_b,  1572864, 1572864);
    conv_kernel<<<dim3(1024), blk, 0, stream>>>(W_uk,  Wuk_b,  1048576, 1048576);
    conv_kernel<<<dim3(1024), blk, 0, stream>>>(W_uv,  Wuv_b,  1048576, 1048576);
    conv_kernel<<<dim3(4096), blk, 0, stream>>>(W_out, Wout_b, 4194304, 4194304);

    // projections
    gemm_bf16<0><<<dim3(12, 32), blk, 0, stream>>>(xb,   Wdq_b,  b_dq,  c_q,    4096, 1536, 2048);
    gemm_bf16<0><<<dim3( 4, 32), blk, 0, stream>>>(xb,   Wdkv_b, b_dkv, c_kv,   4096,  512, 2048);
    gemm_bf16<0><<<dim3( 1, 32), blk, 0, stream>>>(xb,   Wkr_b,  b_kr,  kr_raw, 4096,   64, 2048);
    gemm_bf16<1><<<dim3(16, 32), blk, 0, stream>>>(c_q,  Wuq_b,  b_uq,  qp,     4096, 2048, 1536);
    gemm_bf16<0><<<dim3( 8, 32), blk, 0, stream>>>(c_q,  Wqr_b,  b_qr,  qr_raw, 4096, 1024, 1536);
    rope_q_kernel<<<dim3(16384), blk, 0, stream>>>(qr_raw, fcos, fsin, qp);
    // --- c_q, qr_raw, Wdq_b, Wuq_b, Wqr_b, Wkr_b now dead ---
    gemm_bf16<1><<<dim3(16, 32), blk, 0, stream>>>(c_kv, Wuk_b,  b_uk,  kp,     4096, 2048,  512);
    rope_k_kernel<<<dim3(1024),  blk, 0, stream>>>(kr_raw, fcos, fsin, kp);
    // --- kr_raw now dead ---
    gemm_bf16<2><<<dim3(16, 32), blk, 0, stream>>>(c_kv, Wuv_b,  b_uv,  vtb,    4096, 2048,  512);
    // --- c_kv now dead ---

    // attention (xb dead -> yf alias safe)
    attn_mfma2<<<dim3(16, 32), blk, 0, stream>>>(qp, kp, vtb, yf);

    // output projection
    gemm_bf16<3><<<dim3(16, 32), blk, 0, stream>>>(yf, Wout_b, b_out, d_out, 4096, 2048, 2048);
}

// Round 8
// 467.538 us; speedup vs baseline: 35.1599x; 1.3469x over previous
//
#include <hip/hip_runtime.h>
#include <hip/hip_bf16.h>
#include <stdint.h>

// MLA forward, B=2 S=2048 DIM=2048 NH=16 HD=128 HDR=64 DCKV=512 DCQ=1536
// Round 8: causal load-balance for attention. R6/R7 blocks had 16:1 work
// variance (makespan = heaviest). New attn: QBLK=64, block i runs q-subtiles
// (31-i) then (i) -> exactly 33 KV-tiles per block, all 512 blocks equal.
// Inner loop is the R6-verified stage->barrier->compute form (no T14/T5/cap;
// R7's attn regression was the VGPR cap spilling the prefetch state).
// GEMM: R7 gld16 m97 structure (validated win, ~90us).
//
// Reference reshape quirk: q = concat([uq(2048), rq(1024)]).reshape(...,16,192)
// -> head h owns FLAT dims [192h,192h+192) of the concat (same for k).

typedef __bf16 bf16x8 __attribute__((ext_vector_type(8)));
typedef float  f32x4  __attribute__((ext_vector_type(4)));

__device__ __forceinline__ uint16_t f2bf(float f) {
    uint32_t u = __builtin_bit_cast(uint32_t, f);
    u = (u + 0x7FFFu + ((u >> 16) & 1u)) >> 16;
    return (uint16_t)u;
}
__device__ __forceinline__ float bf2f(uint16_t h) {
    uint32_t u = ((uint32_t)h) << 16;
    return __builtin_bit_cast(float, u);
}

typedef __attribute__((address_space(3))) uint32_t lds_u32_t;
typedef const __attribute__((address_space(1))) uint32_t glb_u32_t;

// async global->LDS, 16B per lane. LDS dest = wave-uniform base + lane*16.
__device__ __forceinline__ void gld16(const void* g, const void* l) {
    __builtin_amdgcn_global_load_lds((glb_u32_t*)(uintptr_t)g,
                                     (lds_u32_t*)(uint32_t)(uintptr_t)l, 16, 0, 0);
}

// ---------------------------------------------------------------------------
// fp32 -> bf16 conversion (zero-fills dst beyond n_src, for padded W_kr)
// ---------------------------------------------------------------------------
__global__ __launch_bounds__(256)
void conv_kernel(const float* __restrict__ src, uint16_t* __restrict__ dst,
                 int n_src, int n_dst)
{
    int i = (blockIdx.x * 256 + threadIdx.x) << 2;
    if (i >= n_dst) return;
    ushort4 o;
    if (i < n_src) {
        float4 v = *(const float4*)(src + i);
        o.x = f2bf(v.x); o.y = f2bf(v.y); o.z = f2bf(v.z); o.w = f2bf(v.w);
    } else {
        o.x = 0; o.y = 0; o.z = 0; o.w = 0;
    }
    *(ushort4*)(dst + i) = o;
}

// ---------------------------------------------------------------------------
// GEMM: C(M,N) = A(M,K) @ W(N,K)^T + bias. A,W bf16 (W pre-padded to 128-row
// multiples); bias fp32. m97 structure: 128x128 tile, BK=32,
// global_load_lds dwordx4 staging, 2 barriers per K-step. (R7-verified)
// MODE 0: bf16 row-major  MODE 1: qk-pack (flat/192 head split)
// MODE 2: v TRANSPOSED pack vt[b,h,d,s]  MODE 3: fp32 row-major
// ---------------------------------------------------------------------------
template<int MODE>
__global__ __launch_bounds__(256, 2)
void gemm_bf16(const uint16_t* __restrict__ A, const uint16_t* __restrict__ W,
               const float* __restrict__ bias, void* __restrict__ Out,
               int M, int N, int K)
{
    __shared__ __align__(16) uint16_t Alds[128 * 32];
    __shared__ __align__(16) uint16_t Blds[128 * 32];

    const int tid  = threadIdx.x;
    const int lane = tid & 63;
    const int wave = tid >> 6;
    const int wm   = wave >> 1;
    const int wn   = wave & 1;
    const int m0   = blockIdx.y << 7;
    const int n0   = blockIdx.x << 7;

    f32x4 acc[4][4];
    #pragma unroll
    for (int i = 0; i < 4; ++i)
        #pragma unroll
        for (int j = 0; j < 4; ++j)
            acc[i][j] = (f32x4){0.f, 0.f, 0.f, 0.f};

    const int r0 = (wave << 5) + (lane >> 2);
    const int ck = (lane & 3) << 3;
    const uint16_t* gA0 = A + (size_t)(m0 + r0) * K + ck;
    const uint16_t* gA1 = gA0 + (size_t)16 * K;
    const uint16_t* gB0 = W + (size_t)(n0 + r0) * K + ck;
    const uint16_t* gB1 = gB0 + (size_t)16 * K;
    const uint16_t* lA0 = Alds + (wave << 10);
    const uint16_t* lA1 = lA0 + 512;
    const uint16_t* lB0 = Blds + (wave << 10);
    const uint16_t* lB1 = lB0 + 512;

    const int rsel = lane & 15;
    const int g8   = (lane >> 4) << 3;

    const int nK = K >> 5;
    for (int kt = 0; kt < nK; ++kt) {
        __syncthreads();
        gld16(gA0, lA0); gld16(gA1, lA1);
        gld16(gB0, lB0); gld16(gB1, lB1);
        gA0 += 32; gA1 += 32; gB0 += 32; gB1 += 32;
        __syncthreads();

        bf16x8 af[4], bfr[4];
        #pragma unroll
        for (int i = 0; i < 4; ++i)
            af[i] = *(const bf16x8*)&Alds[(((wm << 6) + (i << 4) + rsel) << 5) + g8];
        #pragma unroll
        for (int j = 0; j < 4; ++j)
            bfr[j] = *(const bf16x8*)&Blds[(((wn << 6) + (j << 4) + rsel) << 5) + g8];

        #pragma unroll
        for (int i = 0; i < 4; ++i)
            #pragma unroll
            for (int j = 0; j < 4; ++j)
                acc[i][j] = __builtin_amdgcn_mfma_f32_16x16x32_bf16(af[i], bfr[j], acc[i][j], 0, 0, 0);
    }

    // epilogue: D lane map: col = lane&15, row = 4*(lane>>4)+r
    const int col = lane & 15;
    const int rg  = lane >> 4;
    #pragma unroll
    for (int i = 0; i < 4; ++i) {
        #pragma unroll
        for (int j = 0; j < 4; ++j) {
            int n = n0 + (wn << 6) + (j << 4) + col;
            if (n >= N) continue;
            float bv = bias[n];
            float v[4];
            #pragma unroll
            for (int r = 0; r < 4; ++r) v[r] = acc[i][j][r] + bv;
            int mbase = m0 + (wm << 6) + (i << 4) + (rg << 2);
            if (MODE == 0) {
                #pragma unroll
                for (int r = 0; r < 4; ++r)
                    ((uint16_t*)Out)[(size_t)(mbase + r) * N + n] = f2bf(v[r]);
            } else if (MODE == 1) {
                int hh = n / 192, d = n - hh * 192;
                int b = mbase >> 11, s = mbase & 2047;
                uint16_t* o = (uint16_t*)Out + (((size_t)(b * 16 + hh) * 2048 + s) * 192) + d;
                #pragma unroll
                for (int r = 0; r < 4; ++r) o[r * 192] = f2bf(v[r]);
            } else if (MODE == 2) {
                int hh = n >> 7, d = n & 127;
                int b = mbase >> 11, s = mbase & 2047;
                ushort4 o;
                o.x = f2bf(v[0]); o.y = f2bf(v[1]); o.z = f2bf(v[2]); o.w = f2bf(v[3]);
                *(ushort4*)&((uint16_t*)Out)[(((size_t)(b * 16 + hh) * 128 + d) * 2048) + s] = o;
            } else {
                #pragma unroll
                for (int r = 0; r < 4; ++r)
                    ((float*)Out)[(size_t)(mbase + r) * N + n] = v[r];
            }
        }
    }
}

// ---------------------------------------------------------------------------
// RoPE kernels (unchanged, verified)
// ---------------------------------------------------------------------------
__global__ __launch_bounds__(256)
void rope_q_kernel(const uint16_t* __restrict__ raw, const float* __restrict__ fc,
                   const float* __restrict__ fs, uint16_t* __restrict__ qp)
{
    int gid = blockIdx.x * 256 + threadIdx.x;
    int m = gid >> 10, n = gid & 1023;
    int hh = n >> 6, d = n & 63;
    int b = m >> 11, s = m & 2047;
    float x  = bf2f(raw[(size_t)m * 1024 + n]);
    float xo = bf2f(raw[(size_t)m * 1024 + hh * 64 + ((d < 32) ? d + 32 : d - 32)]);
    float rot = (d < 32) ? -xo : xo;
    float v = x * fc[s * 64 + d] + rot * fs[s * 64 + d];
    int f = 2048 + n;
    int head = f / 192, dq = f - head * 192;
    qp[(((size_t)(b * 16 + head) * 2048 + s) * 192) + dq] = f2bf(v);
}

__global__ __launch_bounds__(256)
void rope_k_kernel(const uint16_t* __restrict__ raw, const float* __restrict__ fc,
                   const float* __restrict__ fs, uint16_t* __restrict__ kp)
{
    int gid = blockIdx.x * 256 + threadIdx.x;
    int m = gid >> 6, d = gid & 63;
    int b = m >> 11, s = m & 2047;
    float x  = bf2f(raw[(size_t)m * 64 + d]);
    float xo = bf2f(raw[(size_t)m * 64 + ((d < 32) ? d + 32 : d - 32)]);
    float rot = (d < 32) ? -xo : xo;
    uint16_t bv = f2bf(x * fc[s * 64 + d] + rot * fs[s * 64 + d]);
    #pragma unroll
    for (int hh = 0; hh < 16; ++hh) {
        int f = 2048 + hh * 64 + d;
        int head = f / 192, dk = f - head * 192;
        kp[(((size_t)(b * 16 + head) * 2048 + s) * 192) + dk] = bv;
    }
}

// ---------------------------------------------------------------------------
// MFMA flash attention (causal), load-balanced. QBLK=64 (16 rows/wave).
// Block i runs q-subtile (31-i) then (i): 33 KV-tiles each, all blocks equal.
// V pre-transposed (vt[b,h,d,s]) -> Vs[d][kv]. LDS 53.2KB -> 3 blocks/CU.
// ---------------------------------------------------------------------------
__global__ __launch_bounds__(256)
void attn_mfma3(const uint16_t* __restrict__ qp, const uint16_t* __restrict__ kp,
                const uint16_t* __restrict__ vt, uint16_t* __restrict__ yf)
{
    __shared__ uint16_t Ks[64][200];
    __shared__ uint16_t Vs[128][72];
    __shared__ uint16_t Ps[4][16][72];

    const int tid  = threadIdx.x;
    const int lane = tid & 63;
    const int w    = tid >> 6;
    const int g    = lane >> 4;
    const int li   = lane & 15;
    const int bh   = blockIdx.y;
    const int b    = bh >> 4;
    const int h    = bh & 15;

    const size_t qkb = (size_t)bh * 2048 * 192;
    const size_t vtb = (size_t)bh * 128 * 2048;
    const float scl = 0.07216878364870323f * 1.4426950408889634f;  // 1/sqrt(192)*log2e

    for (int pass = 0; pass < 2; ++pass) {
        const int jq = pass ? (int)blockIdx.x : 31 - (int)blockIdx.x;
        const int q0 = jq << 6;

        // Q fragments: wave owns rows q0 + w*16 .. +15
        bf16x8 qf[6];
        #pragma unroll
        for (int kk = 0; kk < 6; ++kk)
            qf[kk] = *(const bf16x8*)(qp + qkb +
                (size_t)(q0 + (w << 4) + li) * 192 + kk * 32 + (g << 3));

        float mst[4], lst[4];
        f32x4 oacc[8];
        #pragma unroll
        for (int r = 0; r < 4; ++r) { mst[r] = -__builtin_inff(); lst[r] = 0.f; }
        #pragma unroll
        for (int ct = 0; ct < 8; ++ct) oacc[ct] = (f32x4){0.f, 0.f, 0.f, 0.f};

        for (int t = 0; t <= jq; ++t) {
            const int j0 = t << 6;
            __syncthreads();   // protects prior tile reads (and prior pass)
            // stage K tile 64x192
            #pragma unroll
            for (int p = 0; p < 6; ++p) {
                int idx = tid + p * 256;
                int r = idx / 24, c8 = (idx - r * 24) << 3;
                *(bf16x8*)&Ks[r][c8] = *(const bf16x8*)(kp + qkb + (size_t)(j0 + r) * 192 + c8);
            }
            // stage V tile: Vs[d][kv] from vt[b,h,d,s]
            #pragma unroll
            for (int p = 0; p < 8; ++p) {
                int idx = tid + p * 256;
                int r = idx >> 4, c4 = (idx & 15) << 2;
                *(ushort4*)&Vs[r][c4] = *(const ushort4*)(vt + vtb + (size_t)r * 2048 + j0 + c4);
            }
            __syncthreads();

            // S = Q K^T
            f32x4 sacc[4];
            #pragma unroll
            for (int c = 0; c < 4; ++c) sacc[c] = (f32x4){0.f, 0.f, 0.f, 0.f};
            #pragma unroll
            for (int c = 0; c < 4; ++c) {
                #pragma unroll
                for (int kk = 0; kk < 6; ++kk) {
                    bf16x8 kf = *(const bf16x8*)&Ks[(c << 4) + li][kk * 32 + (g << 3)];
                    sacc[c] = __builtin_amdgcn_mfma_f32_16x16x32_bf16(qf[kk], kf, sacc[c], 0, 0, 0);
                }
            }

            // online softmax; rows live in 16-lane groups (all 64 lanes active)
            float corr[4];
            #pragma unroll
            for (int r = 0; r < 4; ++r) {
                const int rq = q0 + (w << 4) + (g << 2) + r;
                float sv[4];
                float mx = -__builtin_inff();
                #pragma unroll
                for (int c = 0; c < 4; ++c) {
                    int colk = j0 + (c << 4) + li;
                    sv[c] = (colk <= rq) ? sacc[c][r] * scl : -__builtin_inff();
                    mx = fmaxf(mx, sv[c]);
                }
                #pragma unroll
                for (int off = 8; off >= 1; off >>= 1) mx = fmaxf(mx, __shfl_xor(mx, off, 64));
                float mnew = fmaxf(mst[r], mx);
                corr[r] = exp2f(mst[r] - mnew);
                mst[r] = mnew;
                float psum = 0.f;
                #pragma unroll
                for (int c = 0; c < 4; ++c) {
                    float p = exp2f(sv[c] - mnew);
                    psum += p;
                    Ps[w][(g << 2) + r][(c << 4) + li] = f2bf(p);
                }
                #pragma unroll
                for (int off = 8; off >= 1; off >>= 1) psum += __shfl_xor(psum, off, 64);
                lst[r] = lst[r] * corr[r] + psum;
            }

            // O = O*corr + P V
            #pragma unroll
            for (int ct = 0; ct < 8; ++ct)
                #pragma unroll
                for (int r = 0; r < 4; ++r) oacc[ct][r] *= corr[r];

            bf16x8 pf0 = *(const bf16x8*)&Ps[w][li][(g << 3)];
            bf16x8 pf1 = *(const bf16x8*)&Ps[w][li][32 + (g << 3)];
            #pragma unroll
            for (int ct = 0; ct < 8; ++ct) {
                bf16x8 vf0 = *(const bf16x8*)&Vs[(ct << 4) + li][(g << 3)];
                bf16x8 vf1 = *(const bf16x8*)&Vs[(ct << 4) + li][32 + (g << 3)];
                oacc[ct] = __builtin_amdgcn_mfma_f32_16x16x32_bf16(pf0, vf0, oacc[ct], 0, 0, 0);
                oacc[ct] = __builtin_amdgcn_mfma_f32_16x16x32_bf16(pf1, vf1, oacc[ct], 0, 0, 0);
            }
        }

        #pragma unroll
        for (int r = 0; r < 4; ++r) {
            float inv = 1.f / lst[r];
            int rq = q0 + (w << 4) + (g << 2) + r;
            size_t obase = ((size_t)(b * 2048 + rq) * 2048) + h * 128;
            #pragma unroll
            for (int ct = 0; ct < 8; ++ct)
                yf[obase + (ct << 4) + li] = f2bf(oacc[ct][r] * inv);
        }
    }
}

// ---------------------------------------------------------------------------
extern "C" void kernel_launch(void* const* d_in, const int* in_sizes, int n_in,
                              void* d_out, int out_size, void* d_ws, size_t ws_size,
                              hipStream_t stream)
{
    const float* x     = (const float*)d_in[0];
    const float* fcos  = (const float*)d_in[1];
    const float* fsin  = (const float*)d_in[2];
    const float* W_dq  = (const float*)d_in[3];
    const float* b_dq  = (const float*)d_in[4];
    const float* W_uq  = (const float*)d_in[5];
    const float* b_uq  = (const float*)d_in[6];
    const float* W_qr  = (const float*)d_in[7];
    const float* b_qr  = (const float*)d_in[8];
    const float* W_dkv = (const float*)d_in[9];
    const float* b_dkv = (const float*)d_in[10];
    const float* W_uk  = (const float*)d_in[11];
    const float* b_uk  = (const float*)d_in[12];
    const float* W_uv  = (const float*)d_in[13];
    const float* b_uv  = (const float*)d_in[14];
    const float* W_kr  = (const float*)d_in[15];
    const float* b_kr  = (const float*)d_in[16];
    const float* W_out = (const float*)d_in[17];
    const float* b_out = (const float*)d_in[18];

    char* ws = (char*)d_ws;
    // Layout (R5/R6-verified), max byte = 103,284,736.
    // Aliases: vtb over {Wdq_b,Wuq_b,Wqr_b,Wkr_b,c_q-head} (dead after rope_q);
    //          kp over {c_q-tail, qr_raw} (dead after rope_q); yf = xb.
    uint16_t* xb     = (uint16_t*)(ws + 0);              // 4096x2048        [end 16,777,216]
    uint16_t* Wuk_b  = (uint16_t*)(ws + 16777216);       // 2048x512         [end 18,874,368]
    uint16_t* Wuv_b  = (uint16_t*)(ws + 18874368);       // 2048x512         [end 20,971,520]
    uint16_t* c_kv   = (uint16_t*)(ws + 20971520);       // 4096x512         [end 25,165,824]
    uint16_t* Wdkv_b = (uint16_t*)(ws + 25165824);       // 512x2048         [end 27,262,976]
    uint16_t* Wdq_b  = (uint16_t*)(ws + 27262976);       // 1536x2048        [end 33,554,432]
    uint16_t* Wuq_b  = (uint16_t*)(ws + 33554432);       // 2048x1536        [end 39,845,888]
    uint16_t* Wqr_b  = (uint16_t*)(ws + 39845888);       // 1024x1536        [end 42,991,616]
    uint16_t* Wkr_b  = (uint16_t*)(ws + 42991616);       // 128x2048 pad     [end 43,515,904]
    uint16_t* c_q    = (uint16_t*)(ws + 43515904);       // 4096x1536        [end 56,098,816]
    uint16_t* qr_raw = (uint16_t*)(ws + 56098816);       // 4096x1024        [end 64,487,424]
    uint16_t* vtb    = (uint16_t*)(ws + 27262976);       // (2,16,128,2048)  [end 44,040,192] ALIAS
    uint16_t* kp     = (uint16_t*)(ws + 44040192);       // (2,16,2048,192)  [end 69,206,016] ALIAS
    uint16_t* qp     = (uint16_t*)(ws + 69206016);       // (2,16,2048,192)  [end 94,371,840]
    uint16_t* kr_raw = (uint16_t*)(ws + 94371840);       // 4096x64          [end 94,896,128]
    uint16_t* Wout_b = (uint16_t*)(ws + 94896128);       // 2048x2048        [end 103,284,736]
    uint16_t* yf     = xb;                               // 4096x2048 ALIAS

    dim3 blk(256);
    // bf16 conversions (full element counts — R3-R5 bug was 524288 here)
    conv_kernel<<<dim3(8192), blk, 0, stream>>>(x,     xb,     8388608, 8388608);
    conv_kernel<<<dim3(3072), blk, 0, stream>>>(W_dq,  Wdq_b,  3145728, 3145728);
    conv_kernel<<<dim3(1024), blk, 0, stream>>>(W_dkv, Wdkv_b, 1048576, 1048576);
    conv_kernel<<<dim3( 256), blk, 0, stream>>>(W_kr,  Wkr_b,   131072,  262144);
    conv_kernel<<<dim3(3072), blk, 0, stream>>>(W_uq,  Wuq_b,  3145728, 3145728);
    conv_kernel<<<dim3(1536), blk, 0, stream>>>(W_qr,  Wqr_b,  1572864, 1572864);
    conv_kernel<<<dim3(1024), blk, 0, stream>>>(W_uk,  Wuk_b,  1048576, 1048576);
    conv_kernel<<<dim3(1024), blk, 0, stream>>>(W_uv,  Wuv_b,  1048576, 1048576);
    conv_kernel<<<dim3(4096), blk, 0, stream>>>(W_out, Wout_b, 4194304, 4194304);

    // projections
    gemm_bf16<0><<<dim3(12, 32), blk, 0, stream>>>(xb,   Wdq_b,  b_dq,  c_q,    4096, 1536, 2048);
    gemm_bf16<0><<<dim3( 4, 32), blk, 0, stream>>>(xb,   Wdkv_b, b_dkv, c_kv,   4096,  512, 2048);
    gemm_bf16<0><<<dim3( 1, 32), blk, 0, stream>>>(xb,   Wkr_b,  b_kr,  kr_raw, 4096,   64, 2048);
    gemm_bf16<1><<<dim3(16, 32), blk, 0, stream>>>(c_q,  Wuq_b,  b_uq,  qp,     4096, 2048, 1536);
    gemm_bf16<0><<<dim3( 8, 32), blk, 0, stream>>>(c_q,  Wqr_b,  b_qr,  qr_raw, 4096, 1024, 1536);
    rope_q_kernel<<<dim3(16384), blk, 0, stream>>>(qr_raw, fcos, fsin, qp);
    // --- c_q, qr_raw, Wdq_b, Wuq_b, Wqr_b, Wkr_b now dead ---
    gemm_bf16<1><<<dim3(16, 32), blk, 0, stream>>>(c_kv, Wuk_b,  b_uk,  kp,     4096, 2048,  512);
    rope_k_kernel<<<dim3(1024),  blk, 0, stream>>>(kr_raw, fcos, fsin, kp);
    // --- kr_raw now dead ---
    gemm_bf16<2><<<dim3(16, 32), blk, 0, stream>>>(c_kv, Wuv_b,  b_uv,  vtb,    4096, 2048,  512);
    // --- c_kv now dead ---

    // attention (xb dead -> yf alias safe); 16 balanced pairs x 32 bh
    attn_mfma3<<<dim3(16, 32), blk, 0, stream>>>(qp, kp, vtb, yf);

    // output projection
    gemm_bf16<3><<<dim3(16, 32), blk, 0, stream>>>(yf, Wout_b, b_out, d_out, 4096, 2048, 2048);
}

// Round 9
// 362.189 us; speedup vs baseline: 45.3868x; 1.2909x over previous
//
#include <hip/hip_runtime.h>
#include <hip/hip_bf16.h>
#include <stdint.h>

// MLA forward, B=2 S=2048 DIM=2048 NH=16 HD=128 HDR=64 DCKV=512 DCQ=1536
// Round 9: GEMM fusion along shared-A groups (tails were eating the machine):
//   G1 = dq|dkv|kr  (A=xb,   K=2048, N=2112 -> c_all row-major, stride 2112)
//   G2 = uq|qr      (A=c_q,  K=1536, N=3072 -> qp-pack | qr_raw)
//   G3 = uk|uv      (A=c_kv, K=512,  N=4096 -> kp-pack | vt-pack)
// gemm gets lda + block-uniform bias/output routing (boundaries 1536/2048 are
// multiples of the 128-col block). attn/conv/rope_q identical to R8 (verified);
// rope_k reads kr from c_all (stride 2112).
//
// Reference reshape quirk: q = concat([uq(2048), rq(1024)]).reshape(...,16,192)
// -> head h owns FLAT dims [192h,192h+192) of the concat (same for k).

typedef __bf16 bf16x8 __attribute__((ext_vector_type(8)));
typedef float  f32x4  __attribute__((ext_vector_type(4)));

__device__ __forceinline__ uint16_t f2bf(float f) {
    uint32_t u = __builtin_bit_cast(uint32_t, f);
    u = (u + 0x7FFFu + ((u >> 16) & 1u)) >> 16;
    return (uint16_t)u;
}
__device__ __forceinline__ float bf2f(uint16_t h) {
    uint32_t u = ((uint32_t)h) << 16;
    return __builtin_bit_cast(float, u);
}

typedef __attribute__((address_space(3))) uint32_t lds_u32_t;
typedef const __attribute__((address_space(1))) uint32_t glb_u32_t;

__device__ __forceinline__ void gld16(const void* g, const void* l) {
    __builtin_amdgcn_global_load_lds((glb_u32_t*)(uintptr_t)g,
                                     (lds_u32_t*)(uint32_t)(uintptr_t)l, 16, 0, 0);
}

// ---------------------------------------------------------------------------
// fp32 -> bf16 conversion (zero-fills dst beyond n_src, for padded W_kr)
// ---------------------------------------------------------------------------
__global__ __launch_bounds__(256)
void conv_kernel(const float* __restrict__ src, uint16_t* __restrict__ dst,
                 int n_src, int n_dst)
{
    int i = (blockIdx.x * 256 + threadIdx.x) << 2;
    if (i >= n_dst) return;
    ushort4 o;
    if (i < n_src) {
        float4 v = *(const float4*)(src + i);
        o.x = f2bf(v.x); o.y = f2bf(v.y); o.z = f2bf(v.z); o.w = f2bf(v.w);
    } else {
        o.x = 0; o.y = 0; o.z = 0; o.w = 0;
    }
    *(ushort4*)(dst + i) = o;
}

// ---------------------------------------------------------------------------
// Fused GEMM: C(M,N) = A(M,K;lda) @ W(N,K)^T + bias. A,W bf16; bias fp32.
// m97 structure: 128x128 tile, BK=32, global_load_lds dwordx4, 2 barriers/K.
// Bias: n<s1 -> b0[n] ; n<s2 -> b1[n-s1] ; else b2[n-s2].
// MODE 0: all n -> bf16 row-major O0 stride N
// MODE 3: all n -> fp32 row-major O0 stride N
// MODE 4: n<s1 -> qk-pack O0 ; n>=s1 -> bf16 row-major O1 stride (N-s1)
// MODE 5: n<s1 -> qk-pack O0 ; n>=s1 -> v-transpose-pack O1 (vt[b,h,d,s])
// ---------------------------------------------------------------------------
template<int MODE>
__global__ __launch_bounds__(256, 2)
void gemm_fused(const uint16_t* __restrict__ A, const uint16_t* __restrict__ W,
                const float* __restrict__ b0, const float* __restrict__ b1,
                const float* __restrict__ b2,
                void* __restrict__ O0, void* __restrict__ O1,
                int M, int N, int K, int lda, int s1, int s2)
{
    __shared__ __align__(16) uint16_t Alds[128 * 32];
    __shared__ __align__(16) uint16_t Blds[128 * 32];

    const int tid  = threadIdx.x;
    const int lane = tid & 63;
    const int wave = tid >> 6;
    const int wm   = wave >> 1;
    const int wn   = wave & 1;
    const int m0   = blockIdx.y << 7;
    const int n0   = blockIdx.x << 7;

    f32x4 acc[4][4];
    #pragma unroll
    for (int i = 0; i < 4; ++i)
        #pragma unroll
        for (int j = 0; j < 4; ++j)
            acc[i][j] = (f32x4){0.f, 0.f, 0.f, 0.f};

    const int r0 = (wave << 5) + (lane >> 2);
    const int ck = (lane & 3) << 3;
    const uint16_t* gA0 = A + (size_t)(m0 + r0) * lda + ck;
    const uint16_t* gA1 = gA0 + (size_t)16 * lda;
    const uint16_t* gB0 = W + (size_t)(n0 + r0) * K + ck;
    const uint16_t* gB1 = gB0 + (size_t)16 * K;
    const uint16_t* lA0 = Alds + (wave << 10);
    const uint16_t* lA1 = lA0 + 512;
    const uint16_t* lB0 = Blds + (wave << 10);
    const uint16_t* lB1 = lB0 + 512;

    const int rsel = lane & 15;
    const int g8   = (lane >> 4) << 3;

    const int nK = K >> 5;
    for (int kt = 0; kt < nK; ++kt) {
        __syncthreads();
        gld16(gA0, lA0); gld16(gA1, lA1);
        gld16(gB0, lB0); gld16(gB1, lB1);
        gA0 += 32; gA1 += 32; gB0 += 32; gB1 += 32;
        __syncthreads();

        bf16x8 af[4], bfr[4];
        #pragma unroll
        for (int i = 0; i < 4; ++i)
            af[i] = *(const bf16x8*)&Alds[(((wm << 6) + (i << 4) + rsel) << 5) + g8];
        #pragma unroll
        for (int j = 0; j < 4; ++j)
            bfr[j] = *(const bf16x8*)&Blds[(((wn << 6) + (j << 4) + rsel) << 5) + g8];

        #pragma unroll
        for (int i = 0; i < 4; ++i)
            #pragma unroll
            for (int j = 0; j < 4; ++j)
                acc[i][j] = __builtin_amdgcn_mfma_f32_16x16x32_bf16(af[i], bfr[j], acc[i][j], 0, 0, 0);
    }

    // epilogue: D lane map: col = lane&15, row = 4*(lane>>4)+r
    const int col = lane & 15;
    const int rg  = lane >> 4;
    #pragma unroll
    for (int i = 0; i < 4; ++i) {
        #pragma unroll
        for (int j = 0; j < 4; ++j) {
            int n = n0 + (wn << 6) + (j << 4) + col;
            if (n >= N) continue;
            float bv = (n < s1) ? b0[n] : (n < s2) ? b1[n - s1] : b2[n - s2];
            float v[4];
            #pragma unroll
            for (int r = 0; r < 4; ++r) v[r] = acc[i][j][r] + bv;
            int mbase = m0 + (wm << 6) + (i << 4) + (rg << 2);
            if (MODE == 0) {
                uint16_t* o = (uint16_t*)O0 + (size_t)mbase * N + n;
                #pragma unroll
                for (int r = 0; r < 4; ++r) o[(size_t)r * N] = f2bf(v[r]);
            } else if (MODE == 3) {
                float* o = (float*)O0 + (size_t)mbase * N + n;
                #pragma unroll
                for (int r = 0; r < 4; ++r) o[(size_t)r * N] = v[r];
            } else {
                if (n < s1) {           // qk-pack (n < 2048, hh = n/192)
                    int hh = n / 192, d = n - hh * 192;
                    int b = mbase >> 11, s = mbase & 2047;
                    uint16_t* o = (uint16_t*)O0 + (((size_t)(b * 16 + hh) * 2048 + s) * 192) + d;
                    #pragma unroll
                    for (int r = 0; r < 4; ++r) o[r * 192] = f2bf(v[r]);
                } else if (MODE == 4) { // row-major tail (qr_raw)
                    int nn = n - s1;
                    uint16_t* o = (uint16_t*)O1 + (size_t)mbase * (N - s1) + nn;
                    #pragma unroll
                    for (int r = 0; r < 4; ++r) o[(size_t)r * (N - s1)] = f2bf(v[r]);
                } else {                // MODE 5: v-transpose pack
                    int nn = n - s1;
                    int hh = nn >> 7, d = nn & 127;
                    int b = mbase >> 11, s = mbase & 2047;
                    ushort4 o4;
                    o4.x = f2bf(v[0]); o4.y = f2bf(v[1]); o4.z = f2bf(v[2]); o4.w = f2bf(v[3]);
                    *(ushort4*)&((uint16_t*)O1)[(((size_t)(b * 16 + hh) * 128 + d) * 2048) + s] = o4;
                }
            }
        }
    }
}

// ---------------------------------------------------------------------------
// RoPE kernels. rope_q unchanged (qr_raw stride 1024). rope_k reads kr from
// c_all (column offset pre-applied by caller, row stride = ldr).
// ---------------------------------------------------------------------------
__global__ __launch_bounds__(256)
void rope_q_kernel(const uint16_t* __restrict__ raw, const float* __restrict__ fc,
                   const float* __restrict__ fs, uint16_t* __restrict__ qp)
{
    int gid = blockIdx.x * 256 + threadIdx.x;
    int m = gid >> 10, n = gid & 1023;
    int hh = n >> 6, d = n & 63;
    int b = m >> 11, s = m & 2047;
    float x  = bf2f(raw[(size_t)m * 1024 + n]);
    float xo = bf2f(raw[(size_t)m * 1024 + hh * 64 + ((d < 32) ? d + 32 : d - 32)]);
    float rot = (d < 32) ? -xo : xo;
    float v = x * fc[s * 64 + d] + rot * fs[s * 64 + d];
    int f = 2048 + n;
    int head = f / 192, dq = f - head * 192;
    qp[(((size_t)(b * 16 + head) * 2048 + s) * 192) + dq] = f2bf(v);
}

__global__ __launch_bounds__(256)
void rope_k_kernel(const uint16_t* __restrict__ raw, int ldr,
                   const float* __restrict__ fc, const float* __restrict__ fs,
                   uint16_t* __restrict__ kp)
{
    int gid = blockIdx.x * 256 + threadIdx.x;
    int m = gid >> 6, d = gid & 63;
    int b = m >> 11, s = m & 2047;
    float x  = bf2f(raw[(size_t)m * ldr + d]);
    float xo = bf2f(raw[(size_t)m * ldr + ((d < 32) ? d + 32 : d - 32)]);
    float rot = (d < 32) ? -xo : xo;
    uint16_t bv = f2bf(x * fc[s * 64 + d] + rot * fs[s * 64 + d]);
    #pragma unroll
    for (int hh = 0; hh < 16; ++hh) {
        int f = 2048 + hh * 64 + d;
        int head = f / 192, dk = f - head * 192;
        kp[(((size_t)(b * 16 + head) * 2048 + s) * 192) + dk] = bv;
    }
}

// ---------------------------------------------------------------------------
// MFMA flash attention (causal), load-balanced. Identical to R8 (verified).
// ---------------------------------------------------------------------------
__global__ __launch_bounds__(256)
void attn_mfma3(const uint16_t* __restrict__ qp, const uint16_t* __restrict__ kp,
                const uint16_t* __restrict__ vt, uint16_t* __restrict__ yf)
{
    __shared__ uint16_t Ks[64][200];
    __shared__ uint16_t Vs[128][72];
    __shared__ uint16_t Ps[4][16][72];

    const int tid  = threadIdx.x;
    const int lane = tid & 63;
    const int w    = tid >> 6;
    const int g    = lane >> 4;
    const int li   = lane & 15;
    const int bh   = blockIdx.y;
    const int b    = bh >> 4;
    const int h    = bh & 15;

    const size_t qkb = (size_t)bh * 2048 * 192;
    const size_t vtb = (size_t)bh * 128 * 2048;
    const float scl = 0.07216878364870323f * 1.4426950408889634f;  // 1/sqrt(192)*log2e

    for (int pass = 0; pass < 2; ++pass) {
        const int jq = pass ? (int)blockIdx.x : 31 - (int)blockIdx.x;
        const int q0 = jq << 6;

        bf16x8 qf[6];
        #pragma unroll
        for (int kk = 0; kk < 6; ++kk)
            qf[kk] = *(const bf16x8*)(qp + qkb +
                (size_t)(q0 + (w << 4) + li) * 192 + kk * 32 + (g << 3));

        float mst[4], lst[4];
        f32x4 oacc[8];
        #pragma unroll
        for (int r = 0; r < 4; ++r) { mst[r] = -__builtin_inff(); lst[r] = 0.f; }
        #pragma unroll
        for (int ct = 0; ct < 8; ++ct) oacc[ct] = (f32x4){0.f, 0.f, 0.f, 0.f};

        for (int t = 0; t <= jq; ++t) {
            const int j0 = t << 6;
            __syncthreads();
            #pragma unroll
            for (int p = 0; p < 6; ++p) {
                int idx = tid + p * 256;
                int r = idx / 24, c8 = (idx - r * 24) << 3;
                *(bf16x8*)&Ks[r][c8] = *(const bf16x8*)(kp + qkb + (size_t)(j0 + r) * 192 + c8);
            }
            #pragma unroll
            for (int p = 0; p < 8; ++p) {
                int idx = tid + p * 256;
                int r = idx >> 4, c4 = (idx & 15) << 2;
                *(ushort4*)&Vs[r][c4] = *(const ushort4*)(vt + vtb + (size_t)r * 2048 + j0 + c4);
            }
            __syncthreads();

            f32x4 sacc[4];
            #pragma unroll
            for (int c = 0; c < 4; ++c) sacc[c] = (f32x4){0.f, 0.f, 0.f, 0.f};
            #pragma unroll
            for (int c = 0; c < 4; ++c) {
                #pragma unroll
                for (int kk = 0; kk < 6; ++kk) {
                    bf16x8 kf = *(const bf16x8*)&Ks[(c << 4) + li][kk * 32 + (g << 3)];
                    sacc[c] = __builtin_amdgcn_mfma_f32_16x16x32_bf16(qf[kk], kf, sacc[c], 0, 0, 0);
                }
            }

            float corr[4];
            #pragma unroll
            for (int r = 0; r < 4; ++r) {
                const int rq = q0 + (w << 4) + (g << 2) + r;
                float sv[4];
                float mx = -__builtin_inff();
                #pragma unroll
                for (int c = 0; c < 4; ++c) {
                    int colk = j0 + (c << 4) + li;
                    sv[c] = (colk <= rq) ? sacc[c][r] * scl : -__builtin_inff();
                    mx = fmaxf(mx, sv[c]);
                }
                #pragma unroll
                for (int off = 8; off >= 1; off >>= 1) mx = fmaxf(mx, __shfl_xor(mx, off, 64));
                float mnew = fmaxf(mst[r], mx);
                corr[r] = exp2f(mst[r] - mnew);
                mst[r] = mnew;
                float psum = 0.f;
                #pragma unroll
                for (int c = 0; c < 4; ++c) {
                    float p = exp2f(sv[c] - mnew);
                    psum += p;
                    Ps[w][(g << 2) + r][(c << 4) + li] = f2bf(p);
                }
                #pragma unroll
                for (int off = 8; off >= 1; off >>= 1) psum += __shfl_xor(psum, off, 64);
                lst[r] = lst[r] * corr[r] + psum;
            }

            #pragma unroll
            for (int ct = 0; ct < 8; ++ct)
                #pragma unroll
                for (int r = 0; r < 4; ++r) oacc[ct][r] *= corr[r];

            bf16x8 pf0 = *(const bf16x8*)&Ps[w][li][(g << 3)];
            bf16x8 pf1 = *(const bf16x8*)&Ps[w][li][32 + (g << 3)];
            #pragma unroll
            for (int ct = 0; ct < 8; ++ct) {
                bf16x8 vf0 = *(const bf16x8*)&Vs[(ct << 4) + li][(g << 3)];
                bf16x8 vf1 = *(const bf16x8*)&Vs[(ct << 4) + li][32 + (g << 3)];
                oacc[ct] = __builtin_amdgcn_mfma_f32_16x16x32_bf16(pf0, vf0, oacc[ct], 0, 0, 0);
                oacc[ct] = __builtin_amdgcn_mfma_f32_16x16x32_bf16(pf1, vf1, oacc[ct], 0, 0, 0);
            }
        }

        #pragma unroll
        for (int r = 0; r < 4; ++r) {
            float inv = 1.f / lst[r];
            int rq = q0 + (w << 4) + (g << 2) + r;
            size_t obase = ((size_t)(b * 2048 + rq) * 2048) + h * 128;
            #pragma unroll
            for (int ct = 0; ct < 8; ++ct)
                yf[obase + (ct << 4) + li] = f2bf(oacc[ct][r] * inv);
        }
    }
}

// ---------------------------------------------------------------------------
extern "C" void kernel_launch(void* const* d_in, const int* in_sizes, int n_in,
                              void* d_out, int out_size, void* d_ws, size_t ws_size,
                              hipStream_t stream)
{
    const float* x     = (const float*)d_in[0];
    const float* fcos  = (const float*)d_in[1];
    const float* fsin  = (const float*)d_in[2];
    const float* W_dq  = (const float*)d_in[3];
    const float* b_dq  = (const float*)d_in[4];
    const float* W_uq  = (const float*)d_in[5];
    const float* b_uq  = (const float*)d_in[6];
    const float* W_qr  = (const float*)d_in[7];
    const float* b_qr  = (const float*)d_in[8];
    const float* W_dkv = (const float*)d_in[9];
    const float* b_dkv = (const float*)d_in[10];
    const float* W_uk  = (const float*)d_in[11];
    const float* b_uk  = (const float*)d_in[12];
    const float* W_uv  = (const float*)d_in[13];
    const float* b_uv  = (const float*)d_in[14];
    const float* W_kr  = (const float*)d_in[15];
    const float* b_kr  = (const float*)d_in[16];
    const float* W_out = (const float*)d_in[17];
    const float* b_out = (const float*)d_in[18];

    char* ws = (char*)d_ws;
    // Layout, peak = 109,576,192 bytes (== R1-proven bound). Aliases:
    //   Wcat2/Wcat3 inside xb region (converted AFTER G1 consumes xb; dead
    //     before attn writes yf over the region)
    //   qr_raw at kp base (written G2, read rope_q, clobbered by G3's kp)
    //   Wcat1 at vt base (conv->G1, dead before G3 writes vt)
    uint16_t* xb     = (uint16_t*)(ws + 0);              // 4096x2048   [end 16,777,216]
    uint16_t* Wcat2  = (uint16_t*)(ws + 0);              // 3072x1536   ALIAS (post-G1)
    uint16_t* Wcat3  = (uint16_t*)(ws + 9437184);        // 4096x512    ALIAS (post-G1)
    uint16_t* yf     = (uint16_t*)(ws + 0);              // 4096x2048   ALIAS (attn)
    uint16_t* Wout_b = (uint16_t*)(ws + 16777216);       // 2048x2048   [end 25,165,824]
    uint16_t* qp     = (uint16_t*)(ws + 25165824);       // (2,16,2048,192) [end 50,331,648]
    uint16_t* kp     = (uint16_t*)(ws + 50331648);       // (2,16,2048,192) [end 75,497,472]
    uint16_t* qr_raw = (uint16_t*)(ws + 50331648);       // 4096x1024   ALIAS (pre-G3)
    uint16_t* vt     = (uint16_t*)(ws + 75497472);       // (2,16,128,2048) [end 92,274,688]
    uint16_t* Wcat1  = (uint16_t*)(ws + 75497472);       // 2176x2048   ALIAS (pre-G3)
    uint16_t* c_all  = (uint16_t*)(ws + 92274688);       // 4096x2112   [end 109,576,192]

    dim3 blk(256);
    // Phase 1 conversions: x, Wcat1 = [Wdq(1536) | Wdkv(512) | Wkr(64->128 pad)], Wout.
    conv_kernel<<<dim3(8192), blk, 0, stream>>>(x,     xb,                8388608, 8388608);
    conv_kernel<<<dim3(3072), blk, 0, stream>>>(W_dq,  Wcat1,             3145728, 3145728);
    conv_kernel<<<dim3(1024), blk, 0, stream>>>(W_dkv, Wcat1 + 3145728,   1048576, 1048576);
    conv_kernel<<<dim3( 256), blk, 0, stream>>>(W_kr,  Wcat1 + 4194304,    131072,  262144);
    conv_kernel<<<dim3(4096), blk, 0, stream>>>(W_out, Wout_b,            4194304, 4194304);

    // G1: c_all = xb @ Wcat1^T  (N=2112, bias regions 1536/2048)
    gemm_fused<0><<<dim3(17, 32), blk, 0, stream>>>(
        xb, Wcat1, b_dq, b_dkv, b_kr, c_all, nullptr,
        4096, 2112, 2048, /*lda*/2048, 1536, 2048);
    // --- xb dead; Wcat1 dead ---

    // Phase 2 conversions (into xb region): Wcat2 = [Wuq(2048)|Wqr(1024)] rows x1536,
    // Wcat3 = [Wuk(2048)|Wuv(2048)] rows x512.
    conv_kernel<<<dim3(3072), blk, 0, stream>>>(W_uq, Wcat2,             3145728, 3145728);
    conv_kernel<<<dim3(1536), blk, 0, stream>>>(W_qr, Wcat2 + 3145728,   1572864, 1572864);
    conv_kernel<<<dim3(1024), blk, 0, stream>>>(W_uk, Wcat3,             1048576, 1048576);
    conv_kernel<<<dim3(1024), blk, 0, stream>>>(W_uv, Wcat3 + 1048576,   1048576, 1048576);

    // G2: [qp-pack | qr_raw] = c_q @ Wcat2^T  (A = c_all cols 0..1535)
    gemm_fused<4><<<dim3(24, 32), blk, 0, stream>>>(
        c_all, Wcat2, b_uq, b_qr, b_qr, qp, qr_raw,
        4096, 3072, 1536, /*lda*/2112, 2048, 3072);

    // rope_q BEFORE G3 (G3's kp writes clobber qr_raw alias)
    rope_q_kernel<<<dim3(16384), blk, 0, stream>>>(qr_raw, fcos, fsin, qp);

    // G3: [kp-pack | vt-pack] = c_kv @ Wcat3^T  (A = c_all cols 1536..2047)
    gemm_fused<5><<<dim3(32, 32), blk, 0, stream>>>(
        c_all + 1536, Wcat3, b_uk, b_uv, b_uv, kp, vt,
        4096, 4096, 512, /*lda*/2112, 2048, 4096);

    // rope_k: kr columns live at c_all + 2048, row stride 2112
    rope_k_kernel<<<dim3(1024), blk, 0, stream>>>(c_all + 2048, 2112, fcos, fsin, kp);

    // attention (writes yf over dead Wcat2/Wcat3)
    attn_mfma3<<<dim3(16, 32), blk, 0, stream>>>(qp, kp, vt, yf);

    // output projection
    gemm_fused<3><<<dim3(16, 32), blk, 0, stream>>>(
        yf, Wout_b, b_out, b_out, b_out, d_out, nullptr,
        4096, 2048, 2048, /*lda*/2048, 2048, 2048);
}